// Round 4
// baseline (578.248 us; speedup 1.0000x reference)
//
#include <hip/hip_runtime.h>
#include <hip/hip_bf16.h>
#include <stdint.h>

// F8Linear: y[m,n] = sum_k x[m,k] * (w_f8[n,k] * s) + bias[n]
// M=1024, N=14336, K=4096.
// R12 == R11 resubmitted (R11 bench was an infra failure: container died
//   during push; no dispatch data). Kernel re-audited: uniform barriers,
//   vmcnt ledger closed (enter 6, +12/tile, peak 18, drain to 6), WAR on
//   As[P][0] separated by >=3 barriers + lgkm, compiler-tracked reg waits.
// R11: R10's fused f32->bf16 B staging with a 2-TILE-DEEP B register
//   pipeline (ping-pong sets E/O): tile kt loads B(kt+2), writes B(kt+1).
//   Issue->consume distance ~7 phases; mid-tile vmcnt waits removed; ONE
//   end-of-tile vmcnt(6) (tail 0). ds_writes drain via lgkmcnt(0) BEFORE
//   the barrier. Loop unrolled x2 -> static LDS buffers + reg sets.
// R10 post-mortem: fused GEMM 260 us vs R9 184 — pure stall from ph3/ph4
//   vmcnt gating on B loads issued only 2 phases earlier (L3-miss latency).

#define IN_F   4096
#define OUT_F  14336
#define M_TOT  1024

// legacy fallback tile params
#define BM 128
#define BN 128

// 8-phase kernel params
#define TM 256
#define TN 256
#define TK 64
#define KT8 (IN_F / TK)   // 64

typedef __bf16  bf16x8 __attribute__((ext_vector_type(8)));
typedef __bf16  bf16x4 __attribute__((ext_vector_type(4)));
typedef float   f32x4  __attribute__((ext_vector_type(4)));

__device__ __forceinline__ void async_copy16(const void* g, void* l) {
    __builtin_amdgcn_global_load_lds(
        (const __attribute__((address_space(1))) void*)g,
        (__attribute__((address_space(3))) void*)l,
        16, 0, 0);
}

// ---- detector: bf16-valued f32 words have low16 == 0 over 1024 dwords ----
__global__ void detect_x_dtype(const uint32_t* __restrict__ xb,
                               int* __restrict__ flag) {
    __shared__ int any_low;
    if (threadIdx.x == 0) any_low = 0;
    __syncthreads();
    uint32_t bad = 0;
    for (int i = threadIdx.x; i < 1024; i += 256) bad |= (xb[i] & 0xFFFFu);
    if (bad) atomicOr(&any_low, 1);
    __syncthreads();
    if (threadIdx.x == 0) *flag = (any_low == 0) ? 1 : 0;
}

// ---- cvt_x: 4,194,304 elems -> bf16 (cvt f32-world, copy bf16-world) ----
__global__ __launch_bounds__(256) void cvt_x_kernel(
    const void* __restrict__ xraw, bf16x8* __restrict__ out,
    const int* __restrict__ flag) {
    const int f32w = (*flag != 0);
    const int i = blockIdx.x * 256 + threadIdx.x;   // 0..524287
    if (f32w) {
        const f32x4* in = (const f32x4*)xraw;
        f32x4 a = in[2 * i];
        f32x4 b = in[2 * i + 1];
        bf16x8 o;
        o[0] = (__bf16)a[0]; o[1] = (__bf16)a[1];
        o[2] = (__bf16)a[2]; o[3] = (__bf16)a[3];
        o[4] = (__bf16)b[0]; o[5] = (__bf16)b[1];
        o[6] = (__bf16)b[2]; o[7] = (__bf16)b[3];
        out[i] = o;
    } else {
        out[i] = ((const bf16x8*)xraw)[i];
    }
}

// ---- main GEMM: 256x256 tile, 8-phase, 2-tile-deep fused B staging ----
__global__ __launch_bounds__(512, 2) void gemm_fused_8ph(
    const __bf16* __restrict__ xb,     // [M_TOT][IN_F] bf16 (ws)
    const float*  __restrict__ wf,     // [OUT_F][IN_F] f32 (original input)
    const float*  __restrict__ w_scale,
    const float*  __restrict__ bias,
    void*         __restrict__ yraw,   // f32 or bf16 container per flag
    const int*    __restrict__ flag_p)
{
    // [dbuf][half]: half = 128 rows x 64 cols bf16 = 16 KiB. Total 128 KiB.
    __shared__ __align__(16) __bf16 As[2][2][128 * TK];
    __shared__ __align__(16) __bf16 Bs[2][2][128 * TK];

    const int f32w = (*flag_p != 0);
    const int t    = threadIdx.x;
    const int lane = t & 63;
    const int wv   = t >> 6;     // 0..7
    const int wm   = wv >> 2;    // 0..1
    const int wn   = wv & 3;     // 0..3
    const int lidx = lane & 15;
    const int q    = lane >> 4;

    // 224 blocks = 8 XCDs x 28; per XCD: 7 N-panels x 4 M-tiles (M fastest)
    const int flat = blockIdx.x;
    const int xcd  = flat & 7;
    const int slot = flat >> 3;            // 0..27
    const int ni   = xcd * 7 + (slot >> 2);
    const int mi   = slot & 3;
    const int m0   = mi * TM;
    const int n0   = ni * TN;

    const float scale = w_scale[0];

    const __bf16* gA = xb + (size_t)m0 * IN_F;

    // staging geometry: half-tile = 1024 slots of 8 bf16; 512 threads x 2.
    // slot s -> row = s>>3, phys 16B-group = s&7 holds LOGICAL group
    // (s&7)^(row&7)  (conflict-free swizzle; LDS dest stays linear).
    int srow[2], scgl[2];
    #pragma unroll
    for (int i = 0; i < 2; ++i) {
        const int s = i * 512 + t;
        srow[i] = s >> 3;
        scgl[i] = (s & 7) ^ (srow[i] & 7);
    }

    // B source (f32): per-thread bases for the two slots
    const float* gB0 = wf + (size_t)(n0 + srow[0]) * IN_F + scgl[0] * 8;
    const float* gB1 = wf + (size_t)(n0 + srow[1]) * IN_F + scgl[1] * 8;

    // ds_read byte offsets within one half-buffer (row*128B + physgrp*16B).
    int aoff[4][2], boff[2][2];
    #pragma unroll
    for (int qm = 0; qm < 4; ++qm) {
        const int row = qm * 32 + wm * 16 + lidx;
        #pragma unroll
        for (int kg = 0; kg < 2; ++kg)
            aoff[qm][kg] = row * 128 + (((kg * 4 + q) ^ (row & 7)) * 16);
    }
    #pragma unroll
    for (int qn = 0; qn < 2; ++qn) {
        const int row = qn * 64 + wn * 16 + lidx;
        #pragma unroll
        for (int kg = 0; kg < 2; ++kg)
            boff[qn][kg] = row * 128 + (((kg * 4 + q) ^ (row & 7)) * 16);
    }

    const f32x4 zero4 = {0.f, 0.f, 0.f, 0.f};
    f32x4 acc[8][4];
    #pragma unroll
    for (int i = 0; i < 8; ++i)
        #pragma unroll
        for (int j = 0; j < 4; ++j)
            acc[i][j] = zero4;

    bf16x8 areg[4][2], breg[2][2];
    // 2-tile-deep B staging regs: even/odd tile-parity sets, static-indexed.
    f32x4 RaE[4], RbE[4], RaO[4], RbO[4];

#define STAGE_A(tile, half, BI) do {                                          \
    __bf16* _dst = &As[(BI)][(half)][0];                                      \
    const __bf16* _src = gA + (size_t)(half) * 128 * IN_F + (tile) * TK;      \
    async_copy16(_src + (size_t)srow[0] * IN_F + scgl[0] * 8, _dst + t * 8);  \
    async_copy16(_src + (size_t)srow[1] * IN_F + scgl[1] * 8,                 \
                 _dst + (512 + t) * 8);                                       \
} while (0)

// issue 4 global f32x4 loads (2 slots x 2) for half-tile (tile,half) of B
#define B_LOAD(tile, half, Rv) do {                                           \
    const float* _p0 = gB0 + (size_t)(half) * 128 * IN_F + (tile) * TK;       \
    const float* _p1 = gB1 + (size_t)(half) * 128 * IN_F + (tile) * TK;       \
    Rv[0] = *(const f32x4*)_p0;                                               \
    Rv[1] = *(const f32x4*)(_p0 + 4);                                         \
    Rv[2] = *(const f32x4*)_p1;                                               \
    Rv[3] = *(const f32x4*)(_p1 + 4);                                         \
} while (0)

// cvt + ds_write of a staged half-tile (dest linear in slot id)
#define B_WRITE(half, BI, Rv) do {                                            \
    __bf16* _d = &Bs[(BI)][(half)][0];                                        \
    bf16x8 _o;                                                                \
    _o[0] = (__bf16)Rv[0][0]; _o[1] = (__bf16)Rv[0][1];                       \
    _o[2] = (__bf16)Rv[0][2]; _o[3] = (__bf16)Rv[0][3];                       \
    _o[4] = (__bf16)Rv[1][0]; _o[5] = (__bf16)Rv[1][1];                       \
    _o[6] = (__bf16)Rv[1][2]; _o[7] = (__bf16)Rv[1][3];                       \
    *(bf16x8*)(_d + (size_t)t * 8) = _o;                                      \
    _o[0] = (__bf16)Rv[2][0]; _o[1] = (__bf16)Rv[2][1];                       \
    _o[2] = (__bf16)Rv[2][2]; _o[3] = (__bf16)Rv[2][3];                       \
    _o[4] = (__bf16)Rv[3][0]; _o[5] = (__bf16)Rv[3][1];                       \
    _o[6] = (__bf16)Rv[3][2]; _o[7] = (__bf16)Rv[3][3];                       \
    *(bf16x8*)(_d + (size_t)(512 + t) * 8) = _o;                              \
} while (0)

#define LOAD_A(base) do {                                                     \
    _Pragma("unroll")                                                         \
    for (int _qm = 0; _qm < 4; ++_qm) {                                       \
        areg[_qm][0] = *(const bf16x8*)((base) + aoff[_qm][0]);               \
        areg[_qm][1] = *(const bf16x8*)((base) + aoff[_qm][1]);               \
    }                                                                         \
} while (0)

#define LOAD_B(base) do {                                                     \
    _Pragma("unroll")                                                         \
    for (int _qn = 0; _qn < 2; ++_qn) {                                       \
        breg[_qn][0] = *(const bf16x8*)((base) + boff[_qn][0]);               \
        breg[_qn][1] = *(const bf16x8*)((base) + boff[_qn][1]);               \
    }                                                                         \
} while (0)

#define MFMA16(MO, NO) do {                                                   \
    __builtin_amdgcn_s_setprio(1);                                            \
    _Pragma("unroll")                                                         \
    for (int _qm = 0; _qm < 4; ++_qm)                                         \
        _Pragma("unroll")                                                     \
        for (int _qn = 0; _qn < 2; ++_qn) {                                   \
            acc[(MO) + _qm][(NO) + _qn] =                                     \
                __builtin_amdgcn_mfma_f32_16x16x32_bf16(                      \
                    areg[_qm][0], breg[_qn][0], acc[(MO) + _qm][(NO) + _qn],  \
                    0, 0, 0);                                                 \
            acc[(MO) + _qm][(NO) + _qn] =                                     \
                __builtin_amdgcn_mfma_f32_16x16x32_bf16(                      \
                    areg[_qm][1], breg[_qn][1], acc[(MO) + _qm][(NO) + _qn],  \
                    0, 0, 0);                                                 \
        }                                                                     \
    __builtin_amdgcn_s_setprio(0);                                            \
} while (0)

#define BARR()    __builtin_amdgcn_s_barrier()
#define LGKM0()   asm volatile("s_waitcnt lgkmcnt(0)" ::: "memory")
#define VMCNT(n)  asm volatile("s_waitcnt vmcnt(" #n ")" ::: "memory")

    // ---- prologue ----
    // group1: B(0,*) loads + A(0,*) dma  [12 loads]
    B_LOAD(0, 0, RaE);
    B_LOAD(0, 1, RbE);
    STAGE_A(0, 0, 0);
    STAGE_A(0, 1, 0);
    VMCNT(4);            // B(0,*) landed
    B_WRITE(0, 0, RaE);
    B_WRITE(1, 0, RbE);
    // group2: B(1,*) loads + A(1,h0) dma  [10 loads]
    B_LOAD(1, 0, RaO);
    B_LOAD(1, 1, RbO);
    STAGE_A(1, 0, 1);
    VMCNT(6);            // all of group1 done; leaves B(1,h1)x4 + A(1,h0)x2
    LGKM0();             // own ds_writes visible before barrier
    BARR();

    // steady-state invariant entering tile kt:
    //   LDS buf[kt&1] = tile kt complete.  Regs set[(kt+1)&1] = B(kt+1).
    //   vmem outstanding <= 6: B(kt+1,h1)x4 (regs) + A(kt+1,h0)x2 (dma).
    // Per-tile ledger: +12 issued (4+2 ph1, 4 ph2, 2 ph3), peak 18,
    //   end-of-tile vmcnt(6) drains 12 (incl. A(kt+1,h1), B(kt+2,h0)).
#define TILE_BODY(kt, P, QI, RWa, RWb, LDa, LDb) do {                         \
    const char* _a0 = (const char*)&As[(P)][0][0];                            \
    const char* _a1 = (const char*)&As[(P)][1][0];                            \
    const char* _b0 = (const char*)&Bs[(P)][0][0];                            \
    const char* _b1 = (const char*)&Bs[(P)][1][0];                            \
    /* phase 1: (Ah0,Bh0); issue B(kt+2,h0) + A(kt+1,h1) dma */               \
    LOAD_A(_a0);                                                              \
    LOAD_B(_b0);                                                              \
    if ((kt) + 2 < KT8) B_LOAD((kt) + 2, 0, LDa);                             \
    if ((kt) + 1 < KT8) STAGE_A((kt) + 1, 1, QI);                             \
    BARR(); LGKM0();                                                          \
    MFMA16(0, 0);                                                             \
    BARR();                                                                   \
    /* phase 2: (Ah0,Bh1); issue B(kt+2,h1) */                                \
    LOAD_B(_b1);                                                              \
    if ((kt) + 2 < KT8) B_LOAD((kt) + 2, 1, LDb);                             \
    BARR(); LGKM0();                                                          \
    MFMA16(0, 2);                                                             \
    BARR();                                                                   \
    /* phase 3: (Ah1,Bh1); write B(kt+1,h0); issue A(kt+2,h0) dma.    */      \
    /* WAR: Bs[QI][0] last read tile kt-1 ph4 (>=2 barriers ago);     */      \
    /*      As[P][0] last read this tile ph1 (lgkm'd, >=2 barriers).  */      \
    LOAD_A(_a1);                                                              \
    if ((kt) + 1 < KT8) B_WRITE(0, QI, RWa);                                  \
    if ((kt) + 2 < KT8) STAGE_A((kt) + 2, 0, P);                              \
    LGKM0();  /* reads waited + writes visible, pre-barrier */                \
    BARR();                                                                   \
    MFMA16(4, 2);                                                             \
    BARR();                                                                   \
    /* phase 4: (Ah1,Bh0); write B(kt+1,h1) */                                \
    LOAD_B(_b0);                                                              \
    if ((kt) + 1 < KT8) B_WRITE(1, QI, RWb);                                  \
    LGKM0();                                                                  \
    BARR();                                                                   \
    MFMA16(4, 0);                                                             \
    if ((kt) < KT8 - 2) { VMCNT(6); } else { VMCNT(0); }                      \
    BARR();                                                                   \
} while (0)

    for (int it = 0; it < KT8 / 2; ++it) {
        const int kte = 2 * it;
        TILE_BODY(kte,     0, 1, RaO, RbO, RaE, RbE);
        TILE_BODY(kte + 1, 1, 0, RaE, RbE, RaO, RbO);
    }

#undef TILE_BODY
#undef STAGE_A
#undef B_LOAD
#undef B_WRITE
#undef LOAD_A
#undef LOAD_B
#undef MFMA16
#undef BARR
#undef LGKM0
#undef VMCNT

    // epilogue. C/D layout (probe-verified): n = lane&15, m = q*4 + reg.
    // acc[mf][nf]: row = m0 + (mf>>2)*128 + (mf&3)*32 + wm*16 + q*4 + r
    //              col = n0 + (nf>>1)*128 + (nf&1)*64 + wn*16 + lidx
    float bv[4];
    #pragma unroll
    for (int nf = 0; nf < 4; ++nf)
        bv[nf] = bias[n0 + (nf >> 1) * 128 + (nf & 1) * 64 + wn * 16 + lidx];

    if (f32w) {
        float* yf = (float*)yraw;
        #pragma unroll
        for (int mf = 0; mf < 8; ++mf)
            #pragma unroll
            for (int r = 0; r < 4; ++r) {
                const int m = m0 + (mf >> 2) * 128 + (mf & 3) * 32 + wm * 16 + q * 4 + r;
                float* yp = yf + (size_t)m * OUT_F + n0 + wn * 16 + lidx;
                #pragma unroll
                for (int nf = 0; nf < 4; ++nf)
                    yp[(nf >> 1) * 128 + (nf & 1) * 64] =
                        acc[mf][nf][r] * scale + bv[nf];
            }
    } else {
        __bf16* yh = (__bf16*)yraw;
        #pragma unroll
        for (int mf = 0; mf < 8; ++mf)
            #pragma unroll
            for (int r = 0; r < 4; ++r) {
                const int m = m0 + (mf >> 2) * 128 + (mf & 3) * 32 + wm * 16 + q * 4 + r;
                __bf16* yp = yh + (size_t)m * OUT_F + n0 + wn * 16 + lidx;
                #pragma unroll
                for (int nf = 0; nf < 4; ++nf)
                    yp[(nf >> 1) * 128 + (nf & 1) * 64] =
                        (__bf16)(acc[mf][nf][r] * scale + bv[nf]);
            }
    }
}

// ---- fallback (R6 kernel): only if ws_size can't hold cvt_x buffer ----
__global__ __launch_bounds__(256) void f8linear_fallback(
    const void*  __restrict__ xraw,
    const float* __restrict__ wq,
    const float* __restrict__ w_scale,
    const float* __restrict__ bias,
    void*        __restrict__ yraw,
    const int*   __restrict__ flag_p)
{
    __shared__ __align__(16) __bf16 As[BM * 40];
    __shared__ __align__(16) __bf16 Bs[BN * 40];

    const int f32w = (*flag_p != 0);
    const int t    = threadIdx.x;
    const int lane = t & 63;
    const int wv   = t >> 6;
    const int wm   = wv >> 1;
    const int wn   = wv & 1;
    const int lidx = lane & 15;
    const int q    = lane >> 4;

    const int flat = blockIdx.x;
    const int xcd  = flat & 7;
    const int slot = flat >> 3;
    const int ni   = xcd * 14 + (slot >> 3);
    const int mi   = slot & 7;
    const int m0   = mi * BM;
    const int n0   = ni * BN;

    const float scale = w_scale[0];
    const float*  xf = (const float*)xraw;
    const __bf16* xh = (const __bf16*)xraw;

    const int af_row = t >> 3;
    const int af_col = (t & 7) * 4;
    int ah_row[2], ah_cg[2];
    #pragma unroll
    for (int i = 0; i < 2; ++i) {
        const int s = i * 256 + t;
        ah_row[i] = s >> 2;
        ah_cg[i]  = s & 3;
    }
    const int b_row = t >> 3;
    const int b_col = (t & 7) * 4;

    const f32x4 zero4 = {0.f, 0.f, 0.f, 0.f};
    f32x4 acc[4][4];
    #pragma unroll
    for (int i = 0; i < 4; ++i)
        #pragma unroll
        for (int j = 0; j < 4; ++j)
            acc[i][j] = zero4;

    f32x4  aregf[4];
    bf16x8 aregh[2];
    f32x4  breg[4];
    if (f32w) {
        #pragma unroll
        for (int i = 0; i < 4; ++i)
            aregf[i] = *reinterpret_cast<const f32x4*>(
                xf + (size_t)(m0 + af_row + i * 32) * IN_F + af_col);
    } else {
        #pragma unroll
        for (int i = 0; i < 2; ++i)
            aregh[i] = *reinterpret_cast<const bf16x8*>(
                xh + (size_t)(m0 + ah_row[i]) * IN_F + ah_cg[i] * 8);
    }
    #pragma unroll
    for (int i = 0; i < 4; ++i)
        breg[i] = *reinterpret_cast<const f32x4*>(
            wq + (size_t)(n0 + i * 32 + b_row) * IN_F + b_col);

    for (int kt = 0; kt < 128; ++kt) {
        const int k0 = kt * 32;
        if (f32w) {
            #pragma unroll
            for (int i = 0; i < 4; ++i) {
                bf16x4 pk;
                pk[0] = (__bf16)aregf[i][0];
                pk[1] = (__bf16)aregf[i][1];
                pk[2] = (__bf16)aregf[i][2];
                pk[3] = (__bf16)aregf[i][3];
                *reinterpret_cast<bf16x4*>(As + (af_row + i * 32) * 40 + af_col) = pk;
            }
        } else {
            #pragma unroll
            for (int i = 0; i < 2; ++i)
                *reinterpret_cast<bf16x8*>(As + ah_row[i] * 40 + ah_cg[i] * 8) = aregh[i];
        }
        #pragma unroll
        for (int i = 0; i < 4; ++i) {
            bf16x4 pk;
            pk[0] = (__bf16)breg[i][0];
            pk[1] = (__bf16)breg[i][1];
            pk[2] = (__bf16)breg[i][2];
            pk[3] = (__bf16)breg[i][3];
            *reinterpret_cast<bf16x4*>(Bs + (i * 32 + b_row) * 40 + b_col) = pk;
        }
        __syncthreads();
        if (kt + 1 < 128) {
            const int k1 = k0 + 32;
            if (f32w) {
                #pragma unroll
                for (int i = 0; i < 4; ++i)
                    aregf[i] = *reinterpret_cast<const f32x4*>(
                        xf + (size_t)(m0 + af_row + i * 32) * IN_F + k1 + af_col);
            } else {
                #pragma unroll
                for (int i = 0; i < 2; ++i)
                    aregh[i] = *reinterpret_cast<const bf16x8*>(
                        xh + (size_t)(m0 + ah_row[i]) * IN_F + k1 + ah_cg[i] * 8);
            }
            #pragma unroll
            for (int i = 0; i < 4; ++i)
                breg[i] = *reinterpret_cast<const f32x4*>(
                    wq + (size_t)(n0 + i * 32 + b_row) * IN_F + k1 + b_col);
        }
        bf16x8 afr[4], bfr[4];
        #pragma unroll
        for (int mt = 0; mt < 4; ++mt) {
            const int row = wm * 64 + mt * 16 + lidx;
            afr[mt] = *reinterpret_cast<const bf16x8*>(As + row * 40 + q * 8);
        }
        #pragma unroll
        for (int nt = 0; nt < 4; ++nt) {
            const int row = wn * 64 + nt * 16 + lidx;
            bfr[nt] = *reinterpret_cast<const bf16x8*>(Bs + row * 40 + q * 8);
        }
        #pragma unroll
        for (int mt = 0; mt < 4; ++mt)
            #pragma unroll
            for (int nt = 0; nt < 4; ++nt)
                acc[mt][nt] = __builtin_amdgcn_mfma_f32_16x16x32_bf16(
                    afr[mt], bfr[nt], acc[mt][nt], 0, 0, 0);
        __syncthreads();
    }

    float bv[4];
    #pragma unroll
    for (int nt = 0; nt < 4; ++nt)
        bv[nt] = bias[n0 + wn * 64 + nt * 16 + lidx];

    if (f32w) {
        float* yf = (float*)yraw;
        #pragma unroll
        for (int mt = 0; mt < 4; ++mt)
            #pragma unroll
            for (int r = 0; r < 4; ++r) {
                const int m = m0 + wm * 64 + mt * 16 + q * 4 + r;
                float* yp = yf + (size_t)m * OUT_F + n0 + wn * 64 + lidx;
                #pragma unroll
                for (int nt = 0; nt < 4; ++nt)
                    yp[nt * 16] = acc[mt][nt][r] * scale + bv[nt];
            }
    } else {
        __bf16* yh = (__bf16*)yraw;
        #pragma unroll
        for (int mt = 0; mt < 4; ++mt)
            #pragma unroll
            for (int r = 0; r < 4; ++r) {
                const int m = m0 + wm * 64 + mt * 16 + q * 4 + r;
                __bf16* yp = yh + (size_t)m * OUT_F + n0 + wn * 64 + lidx;
                #pragma unroll
                for (int nt = 0; nt < 4; ++nt)
                    yp[nt * 16] = (__bf16)(acc[mt][nt][r] * scale + bv[nt]);
            }
    }
}

extern "C" void kernel_launch(void* const* d_in, const int* in_sizes, int n_in,
                              void* d_out, int out_size, void* d_ws, size_t ws_size,
                              hipStream_t stream) {
    const void* px = nullptr; const void* pw = nullptr;
    const void* ps = nullptr; const void* pb = nullptr;
    for (int i = 0; i < n_in; ++i) {
        const long sz = in_sizes[i];
        if      (sz == (long)M_TOT * IN_F) px = d_in[i];
        else if (sz == (long)OUT_F * IN_F) pw = d_in[i];
        else if (sz == 1)                  ps = d_in[i];
        else if (sz == OUT_F)              pb = d_in[i];
    }
    if (!px) px = d_in[0];
    if (!pw) pw = d_in[1];
    if (!ps) ps = d_in[2];
    if (!pb) pb = d_in[3];

    const size_t X_BYTES  = (size_t)M_TOT * IN_F * 2;   // 8,388,608
    const size_t FLAG_OFF = X_BYTES;

    if (ws_size >= FLAG_OFF + 16) {
        __bf16* xbf  = (__bf16*)d_ws;
        int*    flag = (int*)((char*)d_ws + FLAG_OFF);

        const int grid8 = (M_TOT / TM) * (OUT_F / TN);  // 224

        detect_x_dtype<<<1, 256, 0, stream>>>((const uint32_t*)px, flag);
        cvt_x_kernel<<<2048, 256, 0, stream>>>(px, (bf16x8*)xbf, flag);
        gemm_fused_8ph<<<grid8, 512, 0, stream>>>(
            xbf, (const float*)pw, (const float*)ps, (const float*)pb,
            d_out, flag);
    } else {
        int* flag = (int*)d_ws;
        const int grid = (M_TOT / BM) * (OUT_F / BN);   // 896
        detect_x_dtype<<<1, 256, 0, stream>>>((const uint32_t*)px, flag);
        f8linear_fallback<<<grid, 256, 0, stream>>>(
            px, (const float*)pw, (const float*)ps, (const float*)pb, d_out, flag);
    }
}

// Round 5
// 467.790 us; speedup vs baseline: 1.2361x; 1.2361x over previous
//
#include <hip/hip_runtime.h>
#include <hip/hip_bf16.h>
#include <stdint.h>

// F8Linear: y[m,n] = sum_k x[m,k] * (w_f8[n,k] * s) + bias[n]
// M=1024, N=14336, K=4096.
// R13: fused f32->bf16 B staging, 1-TILE-DEEP regs (32 VGPR — R10's
//   footprint, no spill), but restructured to ONE wait point per tile:
//   ph1 loads BOTH halves of B(kt+1) (8 x f32x4); end of ph4, the single
//   tile-end vmcnt(2) (3+ phase distance) covers Br + A-dmas; B_WRITEs
//   go right after it, lgkm-drained before the last barrier.
// R12 post-mortem: 2-deep staging spilled (WRITE_SIZE 57->165 MB scratch,
//   GEMM 337 us). acc=128 AGPR leaves only ~128 VGPRs: one staging set max.
// R10 post-mortem: two mid-tile vmcnt stalls (2-phase distance) cost +76 us.

#define IN_F   4096
#define OUT_F  14336
#define M_TOT  1024

// legacy fallback tile params
#define BM 128
#define BN 128

// 8-phase kernel params
#define TM 256
#define TN 256
#define TK 64
#define KT8 (IN_F / TK)   // 64

typedef __bf16  bf16x8 __attribute__((ext_vector_type(8)));
typedef __bf16  bf16x4 __attribute__((ext_vector_type(4)));
typedef float   f32x4  __attribute__((ext_vector_type(4)));

__device__ __forceinline__ void async_copy16(const void* g, void* l) {
    __builtin_amdgcn_global_load_lds(
        (const __attribute__((address_space(1))) void*)g,
        (__attribute__((address_space(3))) void*)l,
        16, 0, 0);
}

// ---- detector: bf16-valued f32 words have low16 == 0 over 1024 dwords ----
__global__ void detect_x_dtype(const uint32_t* __restrict__ xb,
                               int* __restrict__ flag) {
    __shared__ int any_low;
    if (threadIdx.x == 0) any_low = 0;
    __syncthreads();
    uint32_t bad = 0;
    for (int i = threadIdx.x; i < 1024; i += 256) bad |= (xb[i] & 0xFFFFu);
    if (bad) atomicOr(&any_low, 1);
    __syncthreads();
    if (threadIdx.x == 0) *flag = (any_low == 0) ? 1 : 0;
}

// ---- cvt_x: 4,194,304 elems -> bf16 (cvt f32-world, copy bf16-world) ----
__global__ __launch_bounds__(256) void cvt_x_kernel(
    const void* __restrict__ xraw, bf16x8* __restrict__ out,
    const int* __restrict__ flag) {
    const int f32w = (*flag != 0);
    const int i = blockIdx.x * 256 + threadIdx.x;   // 0..524287
    if (f32w) {
        const f32x4* in = (const f32x4*)xraw;
        f32x4 a = in[2 * i];
        f32x4 b = in[2 * i + 1];
        bf16x8 o;
        o[0] = (__bf16)a[0]; o[1] = (__bf16)a[1];
        o[2] = (__bf16)a[2]; o[3] = (__bf16)a[3];
        o[4] = (__bf16)b[0]; o[5] = (__bf16)b[1];
        o[6] = (__bf16)b[2]; o[7] = (__bf16)b[3];
        out[i] = o;
    } else {
        out[i] = ((const bf16x8*)xraw)[i];
    }
}

// ---- main GEMM: 256x256 tile, 8-phase, fused B staging, 1 wait/tile ----
__global__ __launch_bounds__(512, 2) void gemm_fused_8ph(
    const __bf16* __restrict__ xb,     // [M_TOT][IN_F] bf16 (ws)
    const float*  __restrict__ wf,     // [OUT_F][IN_F] f32 (original input)
    const float*  __restrict__ w_scale,
    const float*  __restrict__ bias,
    void*         __restrict__ yraw,   // f32 or bf16 container per flag
    const int*    __restrict__ flag_p)
{
    // [dbuf][half]: half = 128 rows x 64 cols bf16 = 16 KiB. Total 128 KiB.
    __shared__ __align__(16) __bf16 As[2][2][128 * TK];
    __shared__ __align__(16) __bf16 Bs[2][2][128 * TK];

    const int f32w = (*flag_p != 0);
    const int t    = threadIdx.x;
    const int lane = t & 63;
    const int wv   = t >> 6;     // 0..7
    const int wm   = wv >> 2;    // 0..1
    const int wn   = wv & 3;     // 0..3
    const int lidx = lane & 15;
    const int q    = lane >> 4;

    // 224 blocks = 8 XCDs x 28; per XCD: 7 N-panels x 4 M-tiles (M fastest)
    const int flat = blockIdx.x;
    const int xcd  = flat & 7;
    const int slot = flat >> 3;            // 0..27
    const int ni   = xcd * 7 + (slot >> 2);
    const int mi   = slot & 3;
    const int m0   = mi * TM;
    const int n0   = ni * TN;

    const float scale = w_scale[0];

    const __bf16* gA = xb + (size_t)m0 * IN_F;

    // staging geometry: half-tile = 1024 slots of 8 bf16; 512 threads x 2.
    // slot s -> row = s>>3, phys 16B-group = s&7 holds LOGICAL group
    // (s&7)^(row&7)  (conflict-free swizzle; LDS dest stays linear).
    int srow[2], scgl[2];
    #pragma unroll
    for (int i = 0; i < 2; ++i) {
        const int s = i * 512 + t;
        srow[i] = s >> 3;
        scgl[i] = (s & 7) ^ (srow[i] & 7);
    }

    // B source (f32): per-thread bases for the two slots
    const float* gB0 = wf + (size_t)(n0 + srow[0]) * IN_F + scgl[0] * 8;
    const float* gB1 = wf + (size_t)(n0 + srow[1]) * IN_F + scgl[1] * 8;

    // ds_read byte offsets within one half-buffer (row*128B + physgrp*16B).
    int aoff[4][2], boff[2][2];
    #pragma unroll
    for (int qm = 0; qm < 4; ++qm) {
        const int row = qm * 32 + wm * 16 + lidx;
        #pragma unroll
        for (int kg = 0; kg < 2; ++kg)
            aoff[qm][kg] = row * 128 + (((kg * 4 + q) ^ (row & 7)) * 16);
    }
    #pragma unroll
    for (int qn = 0; qn < 2; ++qn) {
        const int row = qn * 64 + wn * 16 + lidx;
        #pragma unroll
        for (int kg = 0; kg < 2; ++kg)
            boff[qn][kg] = row * 128 + (((kg * 4 + q) ^ (row & 7)) * 16);
    }

    const f32x4 zero4 = {0.f, 0.f, 0.f, 0.f};
    f32x4 acc[8][4];
    #pragma unroll
    for (int i = 0; i < 8; ++i)
        #pragma unroll
        for (int j = 0; j < 4; ++j)
            acc[i][j] = zero4;

    bf16x8 areg[4][2], breg[2][2];
    // single-depth B staging regs (32 VGPR) — proven no-spill footprint
    f32x4 Br0[4], Br1[4];

#define STAGE_A(tile, half, BI) do {                                          \
    __bf16* _dst = &As[(BI)][(half)][0];                                      \
    const __bf16* _src = gA + (size_t)(half) * 128 * IN_F + (tile) * TK;      \
    async_copy16(_src + (size_t)srow[0] * IN_F + scgl[0] * 8, _dst + t * 8);  \
    async_copy16(_src + (size_t)srow[1] * IN_F + scgl[1] * 8,                 \
                 _dst + (512 + t) * 8);                                       \
} while (0)

// issue 4 global f32x4 loads (2 slots x 2) for half-tile (tile,half) of B
#define B_LOAD(tile, half, Rv) do {                                           \
    const float* _p0 = gB0 + (size_t)(half) * 128 * IN_F + (tile) * TK;       \
    const float* _p1 = gB1 + (size_t)(half) * 128 * IN_F + (tile) * TK;       \
    Rv[0] = *(const f32x4*)_p0;                                               \
    Rv[1] = *(const f32x4*)(_p0 + 4);                                         \
    Rv[2] = *(const f32x4*)_p1;                                               \
    Rv[3] = *(const f32x4*)(_p1 + 4);                                         \
} while (0)

// cvt + ds_write of a staged half-tile (dest linear in slot id)
#define B_WRITE(half, BI, Rv) do {                                            \
    __bf16* _d = &Bs[(BI)][(half)][0];                                        \
    bf16x8 _o;                                                                \
    _o[0] = (__bf16)Rv[0][0]; _o[1] = (__bf16)Rv[0][1];                       \
    _o[2] = (__bf16)Rv[0][2]; _o[3] = (__bf16)Rv[0][3];                       \
    _o[4] = (__bf16)Rv[1][0]; _o[5] = (__bf16)Rv[1][1];                       \
    _o[6] = (__bf16)Rv[1][2]; _o[7] = (__bf16)Rv[1][3];                       \
    *(bf16x8*)(_d + (size_t)t * 8) = _o;                                      \
    _o[0] = (__bf16)Rv[2][0]; _o[1] = (__bf16)Rv[2][1];                       \
    _o[2] = (__bf16)Rv[2][2]; _o[3] = (__bf16)Rv[2][3];                       \
    _o[4] = (__bf16)Rv[3][0]; _o[5] = (__bf16)Rv[3][1];                       \
    _o[6] = (__bf16)Rv[3][2]; _o[7] = (__bf16)Rv[3][3];                       \
    *(bf16x8*)(_d + (size_t)(512 + t) * 8) = _o;                              \
} while (0)

#define LOAD_A(base) do {                                                     \
    _Pragma("unroll")                                                         \
    for (int _qm = 0; _qm < 4; ++_qm) {                                       \
        areg[_qm][0] = *(const bf16x8*)((base) + aoff[_qm][0]);               \
        areg[_qm][1] = *(const bf16x8*)((base) + aoff[_qm][1]);               \
    }                                                                         \
} while (0)

#define LOAD_B(base) do {                                                     \
    _Pragma("unroll")                                                         \
    for (int _qn = 0; _qn < 2; ++_qn) {                                       \
        breg[_qn][0] = *(const bf16x8*)((base) + boff[_qn][0]);               \
        breg[_qn][1] = *(const bf16x8*)((base) + boff[_qn][1]);               \
    }                                                                         \
} while (0)

#define MFMA16(MO, NO) do {                                                   \
    __builtin_amdgcn_s_setprio(1);                                            \
    _Pragma("unroll")                                                         \
    for (int _qm = 0; _qm < 4; ++_qm)                                         \
        _Pragma("unroll")                                                     \
        for (int _qn = 0; _qn < 2; ++_qn) {                                   \
            acc[(MO) + _qm][(NO) + _qn] =                                     \
                __builtin_amdgcn_mfma_f32_16x16x32_bf16(                      \
                    areg[_qm][0], breg[_qn][0], acc[(MO) + _qm][(NO) + _qn],  \
                    0, 0, 0);                                                 \
            acc[(MO) + _qm][(NO) + _qn] =                                     \
                __builtin_amdgcn_mfma_f32_16x16x32_bf16(                      \
                    areg[_qm][1], breg[_qn][1], acc[(MO) + _qm][(NO) + _qn],  \
                    0, 0, 0);                                                 \
        }                                                                     \
    __builtin_amdgcn_s_setprio(0);                                            \
} while (0)

#define BARR()    __builtin_amdgcn_s_barrier()
#define LGKM0()   asm volatile("s_waitcnt lgkmcnt(0)" ::: "memory")
#define VMCNT(n)  asm volatile("s_waitcnt vmcnt(" #n ")" ::: "memory")

    // ---- prologue ----
    B_LOAD(0, 0, Br0);
    B_LOAD(0, 1, Br1);
    STAGE_A(0, 0, 0);
    STAGE_A(0, 1, 0);
    VMCNT(4);            // drains Br0+Br1 (oldest 8); A(0,*) x4 in flight
    B_WRITE(0, 0, Br0);
    B_WRITE(1, 0, Br1);
    STAGE_A(1, 0, 1);
    VMCNT(2);            // drains A(0,h0)+A(0,h1); leaves A(1,h0) x2
    LGKM0();             // own ds_writes visible before barrier
    BARR();

    // steady-state invariant entering tile kt:
    //   LDS buf[kt&1] = tile kt complete. vmem outstanding: A(kt+1,h0) x2.
    // Ledger per tile: +8 Br (ph1), +2 A(kt+1,h1) (ph2), +2 A(kt+2,h0)
    //   (ph3); tile-end vmcnt(2) drains 12, leaves A(kt+2,h0) x2.
#define TILE_BODY(kt, P, QI) do {                                             \
    const char* _a0 = (const char*)&As[(P)][0][0];                            \
    const char* _a1 = (const char*)&As[(P)][1][0];                            \
    const char* _b0 = (const char*)&Bs[(P)][0][0];                            \
    const char* _b1 = (const char*)&Bs[(P)][1][0];                            \
    /* phase 1: (Ah0,Bh0); issue ALL of B(kt+1) [8 f32x4 loads] */            \
    LOAD_A(_a0);                                                              \
    LOAD_B(_b0);                                                              \
    if ((kt) + 1 < KT8) { B_LOAD((kt) + 1, 0, Br0);                           \
                          B_LOAD((kt) + 1, 1, Br1); }                         \
    BARR(); LGKM0();                                                          \
    MFMA16(0, 0);                                                             \
    BARR();                                                                   \
    /* phase 2: (Ah0,Bh1); issue A(kt+1,h1) dma */                            \
    LOAD_B(_b1);                                                              \
    if ((kt) + 1 < KT8) STAGE_A((kt) + 1, 1, QI);                             \
    BARR(); LGKM0();                                                          \
    MFMA16(0, 2);                                                             \
    BARR();                                                                   \
    /* phase 3: (Ah1,Bh1); issue A(kt+2,h0) dma (WAR: As[P][0] read    */     \
    /* completed at ph1 LGKM0, two barriers ago)                       */     \
    LOAD_A(_a1);                                                              \
    if ((kt) + 2 < KT8) STAGE_A((kt) + 2, 0, P);                              \
    BARR(); LGKM0();                                                          \
    MFMA16(4, 2);                                                             \
    BARR();                                                                   \
    /* phase 4: (Ah1,Bh0); single tile-end wait, then write B(kt+1).   */     \
    /* vmcnt(2): drains Br (3-phase distance) + A(kt+1,*) dmas;        */     \
    /* leaves A(kt+2,h0). WAR on Bs[QI]: last read tile kt-1 ph4,      */     \
    /* >=4 barriers ago.                                               */     \
    LOAD_B(_b0);                                                              \
    BARR(); LGKM0();                                                          \
    MFMA16(4, 0);                                                             \
    if ((kt) < KT8 - 2)      { VMCNT(2); }                                    \
    else                     { VMCNT(0); }                                    \
    if ((kt) + 1 < KT8) {                                                     \
        B_WRITE(0, QI, Br0);                                                  \
        B_WRITE(1, QI, Br1);                                                  \
        LGKM0();                                                              \
    }                                                                         \
    BARR();                                                                   \
} while (0)

    for (int it = 0; it < KT8 / 2; ++it) {
        const int kte = 2 * it;
        TILE_BODY(kte,     0, 1);
        TILE_BODY(kte + 1, 1, 0);
    }

#undef TILE_BODY
#undef STAGE_A
#undef B_LOAD
#undef B_WRITE
#undef LOAD_A
#undef LOAD_B
#undef MFMA16
#undef BARR
#undef LGKM0
#undef VMCNT

    // epilogue. C/D layout (probe-verified): n = lane&15, m = q*4 + reg.
    // acc[mf][nf]: row = m0 + (mf>>2)*128 + (mf&3)*32 + wm*16 + q*4 + r
    //              col = n0 + (nf>>1)*128 + (nf&1)*64 + wn*16 + lidx
    float bv[4];
    #pragma unroll
    for (int nf = 0; nf < 4; ++nf)
        bv[nf] = bias[n0 + (nf >> 1) * 128 + (nf & 1) * 64 + wn * 16 + lidx];

    if (f32w) {
        float* yf = (float*)yraw;
        #pragma unroll
        for (int mf = 0; mf < 8; ++mf)
            #pragma unroll
            for (int r = 0; r < 4; ++r) {
                const int m = m0 + (mf >> 2) * 128 + (mf & 3) * 32 + wm * 16 + q * 4 + r;
                float* yp = yf + (size_t)m * OUT_F + n0 + wn * 16 + lidx;
                #pragma unroll
                for (int nf = 0; nf < 4; ++nf)
                    yp[(nf >> 1) * 128 + (nf & 1) * 64] =
                        acc[mf][nf][r] * scale + bv[nf];
            }
    } else {
        __bf16* yh = (__bf16*)yraw;
        #pragma unroll
        for (int mf = 0; mf < 8; ++mf)
            #pragma unroll
            for (int r = 0; r < 4; ++r) {
                const int m = m0 + (mf >> 2) * 128 + (mf & 3) * 32 + wm * 16 + q * 4 + r;
                __bf16* yp = yh + (size_t)m * OUT_F + n0 + wn * 16 + lidx;
                #pragma unroll
                for (int nf = 0; nf < 4; ++nf)
                    yp[(nf >> 1) * 128 + (nf & 1) * 64] =
                        (__bf16)(acc[mf][nf][r] * scale + bv[nf]);
            }
    }
}

// ---- fallback (R6 kernel): only if ws_size can't hold cvt_x buffer ----
__global__ __launch_bounds__(256) void f8linear_fallback(
    const void*  __restrict__ xraw,
    const float* __restrict__ wq,
    const float* __restrict__ w_scale,
    const float* __restrict__ bias,
    void*        __restrict__ yraw,
    const int*   __restrict__ flag_p)
{
    __shared__ __align__(16) __bf16 As[BM * 40];
    __shared__ __align__(16) __bf16 Bs[BN * 40];

    const int f32w = (*flag_p != 0);
    const int t    = threadIdx.x;
    const int lane = t & 63;
    const int wv   = t >> 6;
    const int wm   = wv >> 1;
    const int wn   = wv & 1;
    const int lidx = lane & 15;
    const int q    = lane >> 4;

    const int flat = blockIdx.x;
    const int xcd  = flat & 7;
    const int slot = flat >> 3;
    const int ni   = xcd * 14 + (slot >> 3);
    const int mi   = slot & 7;
    const int m0   = mi * BM;
    const int n0   = ni * BN;

    const float scale = w_scale[0];
    const float*  xf = (const float*)xraw;
    const __bf16* xh = (const __bf16*)xraw;

    const int af_row = t >> 3;
    const int af_col = (t & 7) * 4;
    int ah_row[2], ah_cg[2];
    #pragma unroll
    for (int i = 0; i < 2; ++i) {
        const int s = i * 256 + t;
        ah_row[i] = s >> 2;
        ah_cg[i]  = s & 3;
    }
    const int b_row = t >> 3;
    const int b_col = (t & 7) * 4;

    const f32x4 zero4 = {0.f, 0.f, 0.f, 0.f};
    f32x4 acc[4][4];
    #pragma unroll
    for (int i = 0; i < 4; ++i)
        #pragma unroll
        for (int j = 0; j < 4; ++j)
            acc[i][j] = zero4;

    f32x4  aregf[4];
    bf16x8 aregh[2];
    f32x4  breg[4];
    if (f32w) {
        #pragma unroll
        for (int i = 0; i < 4; ++i)
            aregf[i] = *reinterpret_cast<const f32x4*>(
                xf + (size_t)(m0 + af_row + i * 32) * IN_F + af_col);
    } else {
        #pragma unroll
        for (int i = 0; i < 2; ++i)
            aregh[i] = *reinterpret_cast<const bf16x8*>(
                xh + (size_t)(m0 + ah_row[i]) * IN_F + ah_cg[i] * 8);
    }
    #pragma unroll
    for (int i = 0; i < 4; ++i)
        breg[i] = *reinterpret_cast<const f32x4*>(
            wq + (size_t)(n0 + i * 32 + b_row) * IN_F + b_col);

    for (int kt = 0; kt < 128; ++kt) {
        const int k0 = kt * 32;
        if (f32w) {
            #pragma unroll
            for (int i = 0; i < 4; ++i) {
                bf16x4 pk;
                pk[0] = (__bf16)aregf[i][0];
                pk[1] = (__bf16)aregf[i][1];
                pk[2] = (__bf16)aregf[i][2];
                pk[3] = (__bf16)aregf[i][3];
                *reinterpret_cast<bf16x4*>(As + (af_row + i * 32) * 40 + af_col) = pk;
            }
        } else {
            #pragma unroll
            for (int i = 0; i < 2; ++i)
                *reinterpret_cast<bf16x8*>(As + ah_row[i] * 40 + ah_cg[i] * 8) = aregh[i];
        }
        #pragma unroll
        for (int i = 0; i < 4; ++i) {
            bf16x4 pk;
            pk[0] = (__bf16)breg[i][0];
            pk[1] = (__bf16)breg[i][1];
            pk[2] = (__bf16)breg[i][2];
            pk[3] = (__bf16)breg[i][3];
            *reinterpret_cast<bf16x4*>(Bs + (i * 32 + b_row) * 40 + b_col) = pk;
        }
        __syncthreads();
        if (kt + 1 < 128) {
            const int k1 = k0 + 32;
            if (f32w) {
                #pragma unroll
                for (int i = 0; i < 4; ++i)
                    aregf[i] = *reinterpret_cast<const f32x4*>(
                        xf + (size_t)(m0 + af_row + i * 32) * IN_F + k1 + af_col);
            } else {
                #pragma unroll
                for (int i = 0; i < 2; ++i)
                    aregh[i] = *reinterpret_cast<const bf16x8*>(
                        xh + (size_t)(m0 + ah_row[i]) * IN_F + k1 + ah_cg[i] * 8);
            }
            #pragma unroll
            for (int i = 0; i < 4; ++i)
                breg[i] = *reinterpret_cast<const f32x4*>(
                    wq + (size_t)(n0 + i * 32 + b_row) * IN_F + k1 + b_col);
        }
        bf16x8 afr[4], bfr[4];
        #pragma unroll
        for (int mt = 0; mt < 4; ++mt) {
            const int row = wm * 64 + mt * 16 + lidx;
            afr[mt] = *reinterpret_cast<const bf16x8*>(As + row * 40 + q * 8);
        }
        #pragma unroll
        for (int nt = 0; nt < 4; ++nt) {
            const int row = wn * 64 + nt * 16 + lidx;
            bfr[nt] = *reinterpret_cast<const bf16x8*>(Bs + row * 40 + q * 8);
        }
        #pragma unroll
        for (int mt = 0; mt < 4; ++mt)
            #pragma unroll
            for (int nt = 0; nt < 4; ++nt)
                acc[mt][nt] = __builtin_amdgcn_mfma_f32_16x16x32_bf16(
                    afr[mt], bfr[nt], acc[mt][nt], 0, 0, 0);
        __syncthreads();
    }

    float bv[4];
    #pragma unroll
    for (int nt = 0; nt < 4; ++nt)
        bv[nt] = bias[n0 + wn * 64 + nt * 16 + lidx];

    if (f32w) {
        float* yf = (float*)yraw;
        #pragma unroll
        for (int mt = 0; mt < 4; ++mt)
            #pragma unroll
            for (int r = 0; r < 4; ++r) {
                const int m = m0 + wm * 64 + mt * 16 + q * 4 + r;
                float* yp = yf + (size_t)m * OUT_F + n0 + wn * 64 + lidx;
                #pragma unroll
                for (int nt = 0; nt < 4; ++nt)
                    yp[nt * 16] = acc[mt][nt][r] * scale + bv[nt];
            }
    } else {
        __bf16* yh = (__bf16*)yraw;
        #pragma unroll
        for (int mt = 0; mt < 4; ++mt)
            #pragma unroll
            for (int r = 0; r < 4; ++r) {
                const int m = m0 + wm * 64 + mt * 16 + q * 4 + r;
                __bf16* yp = yh + (size_t)m * OUT_F + n0 + wn * 64 + lidx;
                #pragma unroll
                for (int nt = 0; nt < 4; ++nt)
                    yp[nt * 16] = (__bf16)(acc[mt][nt][r] * scale + bv[nt]);
            }
    }
}

extern "C" void kernel_launch(void* const* d_in, const int* in_sizes, int n_in,
                              void* d_out, int out_size, void* d_ws, size_t ws_size,
                              hipStream_t stream) {
    const void* px = nullptr; const void* pw = nullptr;
    const void* ps = nullptr; const void* pb = nullptr;
    for (int i = 0; i < n_in; ++i) {
        const long sz = in_sizes[i];
        if      (sz == (long)M_TOT * IN_F) px = d_in[i];
        else if (sz == (long)OUT_F * IN_F) pw = d_in[i];
        else if (sz == 1)                  ps = d_in[i];
        else if (sz == OUT_F)              pb = d_in[i];
    }
    if (!px) px = d_in[0];
    if (!pw) pw = d_in[1];
    if (!ps) ps = d_in[2];
    if (!pb) pb = d_in[3];

    const size_t X_BYTES  = (size_t)M_TOT * IN_F * 2;   // 8,388,608
    const size_t FLAG_OFF = X_BYTES;

    if (ws_size >= FLAG_OFF + 16) {
        __bf16* xbf  = (__bf16*)d_ws;
        int*    flag = (int*)((char*)d_ws + FLAG_OFF);

        const int grid8 = (M_TOT / TM) * (OUT_F / TN);  // 224

        detect_x_dtype<<<1, 256, 0, stream>>>((const uint32_t*)px, flag);
        cvt_x_kernel<<<2048, 256, 0, stream>>>(px, (bf16x8*)xbf, flag);
        gemm_fused_8ph<<<grid8, 512, 0, stream>>>(
            xbf, (const float*)pw, (const float*)ps, (const float*)pb,
            d_out, flag);
    } else {
        int* flag = (int*)d_ws;
        const int grid = (M_TOT / BM) * (OUT_F / BN);   // 896
        detect_x_dtype<<<1, 256, 0, stream>>>((const uint32_t*)px, flag);
        f8linear_fallback<<<grid, 256, 0, stream>>>(
            px, (const float*)pw, (const float*)ps, (const float*)pb, d_out, flag);
    }
}

// Round 6
// 464.997 us; speedup vs baseline: 1.2436x; 1.0060x over previous
//
#include <hip/hip_runtime.h>
#include <hip/hip_bf16.h>
#include <stdint.h>

// F8Linear: y[m,n] = sum_k x[m,k] * (w_f8[n,k] * s) + bias[n]
// M=1024, N=14336, K=4096.
// R14: BARRIER COLLAPSE. Hazards are tile-granular (staging targets the
//   other dbuf; all phases read the resident buffer), so the 8-phase
//   structure's 8 barriers/tile protect nothing intra-tile. New tile body:
//   {issue B loads + A DMAs for kt+1} then straight-line 24 ds_read + 64
//   MFMA (compiler schedules, exact counted lgkm waits), then ONE
//   vmcnt(0) + B_WRITE + lgkmcnt(0) + s_barrier. setprio dropped (m190:
//   hurts lockstep GEMM; no role-split left).
// R13 post-mortem: 217 us, MfmaUtil 22%, spill fixed. Cycle ledger: MFMA
//   2480 cyc/tile + reads ~600 vs measured ~8000 — gap is 8 barrier
//   convoys + forced full lgkm drains per phase. This round removes 7/8.

#define IN_F   4096
#define OUT_F  14336
#define M_TOT  1024

// legacy fallback tile params
#define BM 128
#define BN 128

// main kernel params
#define TM 256
#define TN 256
#define TK 64
#define KT8 (IN_F / TK)   // 64

typedef __bf16  bf16x8 __attribute__((ext_vector_type(8)));
typedef __bf16  bf16x4 __attribute__((ext_vector_type(4)));
typedef float   f32x4  __attribute__((ext_vector_type(4)));

__device__ __forceinline__ void async_copy16(const void* g, void* l) {
    __builtin_amdgcn_global_load_lds(
        (const __attribute__((address_space(1))) void*)g,
        (__attribute__((address_space(3))) void*)l,
        16, 0, 0);
}

// ---- detector: bf16-valued f32 words have low16 == 0 over 1024 dwords ----
__global__ void detect_x_dtype(const uint32_t* __restrict__ xb,
                               int* __restrict__ flag) {
    __shared__ int any_low;
    if (threadIdx.x == 0) any_low = 0;
    __syncthreads();
    uint32_t bad = 0;
    for (int i = threadIdx.x; i < 1024; i += 256) bad |= (xb[i] & 0xFFFFu);
    if (bad) atomicOr(&any_low, 1);
    __syncthreads();
    if (threadIdx.x == 0) *flag = (any_low == 0) ? 1 : 0;
}

// ---- cvt_x: 4,194,304 elems -> bf16 (cvt f32-world, copy bf16-world) ----
__global__ __launch_bounds__(256) void cvt_x_kernel(
    const void* __restrict__ xraw, bf16x8* __restrict__ out,
    const int* __restrict__ flag) {
    const int f32w = (*flag != 0);
    const int i = blockIdx.x * 256 + threadIdx.x;   // 0..524287
    if (f32w) {
        const f32x4* in = (const f32x4*)xraw;
        f32x4 a = in[2 * i];
        f32x4 b = in[2 * i + 1];
        bf16x8 o;
        o[0] = (__bf16)a[0]; o[1] = (__bf16)a[1];
        o[2] = (__bf16)a[2]; o[3] = (__bf16)a[3];
        o[4] = (__bf16)b[0]; o[5] = (__bf16)b[1];
        o[6] = (__bf16)b[2]; o[7] = (__bf16)b[3];
        out[i] = o;
    } else {
        out[i] = ((const bf16x8*)xraw)[i];
    }
}

// ---- main GEMM: 256x256 tile, ONE barrier per K-tile, fused B cvt ----
__global__ __launch_bounds__(512, 2) void gemm_fused_1b(
    const __bf16* __restrict__ xb,     // [M_TOT][IN_F] bf16 (ws)
    const float*  __restrict__ wf,     // [OUT_F][IN_F] f32 (original input)
    const float*  __restrict__ w_scale,
    const float*  __restrict__ bias,
    void*         __restrict__ yraw,   // f32 or bf16 container per flag
    const int*    __restrict__ flag_p)
{
    // [dbuf][half]: half = 128 rows x 64 cols bf16 = 16 KiB. Total 128 KiB.
    __shared__ __align__(16) __bf16 As[2][2][128 * TK];
    __shared__ __align__(16) __bf16 Bs[2][2][128 * TK];

    const int f32w = (*flag_p != 0);
    const int t    = threadIdx.x;
    const int lane = t & 63;
    const int wv   = t >> 6;     // 0..7
    const int wm   = wv >> 2;    // 0..1
    const int wn   = wv & 3;     // 0..3
    const int lidx = lane & 15;
    const int q    = lane >> 4;

    // 224 blocks = 8 XCDs x 28; per XCD: 7 N-panels x 4 M-tiles (M fastest)
    const int flat = blockIdx.x;
    const int xcd  = flat & 7;
    const int slot = flat >> 3;            // 0..27
    const int ni   = xcd * 7 + (slot >> 2);
    const int mi   = slot & 3;
    const int m0   = mi * TM;
    const int n0   = ni * TN;

    const float scale = w_scale[0];

    const __bf16* gA = xb + (size_t)m0 * IN_F;

    // staging geometry: half-tile = 1024 slots of 8 bf16; 512 threads x 2.
    // slot s -> row = s>>3, phys 16B-group = s&7 holds LOGICAL group
    // (s&7)^(row&7)  (conflict-free swizzle; LDS dest stays linear).
    int srow[2], scgl[2];
    #pragma unroll
    for (int i = 0; i < 2; ++i) {
        const int s = i * 512 + t;
        srow[i] = s >> 3;
        scgl[i] = (s & 7) ^ (srow[i] & 7);
    }

    // B source (f32): per-thread bases for the two slots
    const float* gB0 = wf + (size_t)(n0 + srow[0]) * IN_F + scgl[0] * 8;
    const float* gB1 = wf + (size_t)(n0 + srow[1]) * IN_F + scgl[1] * 8;

    // ds_read byte offsets within one half-buffer (row*128B + physgrp*16B).
    int aoff[4][2], boff[2][2];
    #pragma unroll
    for (int qm = 0; qm < 4; ++qm) {
        const int row = qm * 32 + wm * 16 + lidx;
        #pragma unroll
        for (int kg = 0; kg < 2; ++kg)
            aoff[qm][kg] = row * 128 + (((kg * 4 + q) ^ (row & 7)) * 16);
    }
    #pragma unroll
    for (int qn = 0; qn < 2; ++qn) {
        const int row = qn * 64 + wn * 16 + lidx;
        #pragma unroll
        for (int kg = 0; kg < 2; ++kg)
            boff[qn][kg] = row * 128 + (((kg * 4 + q) ^ (row & 7)) * 16);
    }

    const f32x4 zero4 = {0.f, 0.f, 0.f, 0.f};
    f32x4 acc[8][4];
    #pragma unroll
    for (int i = 0; i < 8; ++i)
        #pragma unroll
        for (int j = 0; j < 4; ++j)
            acc[i][j] = zero4;

    bf16x8 areg[4][2], breg[2][2];
    // single-depth B staging regs (32 VGPR) — proven no-spill footprint
    f32x4 Br0[4], Br1[4];

#define STAGE_A(tile, half, BI) do {                                          \
    __bf16* _dst = &As[(BI)][(half)][0];                                      \
    const __bf16* _src = gA + (size_t)(half) * 128 * IN_F + (tile) * TK;      \
    async_copy16(_src + (size_t)srow[0] * IN_F + scgl[0] * 8, _dst + t * 8);  \
    async_copy16(_src + (size_t)srow[1] * IN_F + scgl[1] * 8,                 \
                 _dst + (512 + t) * 8);                                       \
} while (0)

// issue 4 global f32x4 loads (2 slots x 2) for half-tile (tile,half) of B
#define B_LOAD(tile, half, Rv) do {                                           \
    const float* _p0 = gB0 + (size_t)(half) * 128 * IN_F + (tile) * TK;       \
    const float* _p1 = gB1 + (size_t)(half) * 128 * IN_F + (tile) * TK;       \
    Rv[0] = *(const f32x4*)_p0;                                               \
    Rv[1] = *(const f32x4*)(_p0 + 4);                                         \
    Rv[2] = *(const f32x4*)_p1;                                               \
    Rv[3] = *(const f32x4*)(_p1 + 4);                                         \
} while (0)

// cvt + ds_write of a staged half-tile (dest linear in slot id)
#define B_WRITE(half, BI, Rv) do {                                            \
    __bf16* _d = &Bs[(BI)][(half)][0];                                        \
    bf16x8 _o;                                                                \
    _o[0] = (__bf16)Rv[0][0]; _o[1] = (__bf16)Rv[0][1];                       \
    _o[2] = (__bf16)Rv[0][2]; _o[3] = (__bf16)Rv[0][3];                       \
    _o[4] = (__bf16)Rv[1][0]; _o[5] = (__bf16)Rv[1][1];                       \
    _o[6] = (__bf16)Rv[1][2]; _o[7] = (__bf16)Rv[1][3];                       \
    *(bf16x8*)(_d + (size_t)t * 8) = _o;                                      \
    _o[0] = (__bf16)Rv[2][0]; _o[1] = (__bf16)Rv[2][1];                       \
    _o[2] = (__bf16)Rv[2][2]; _o[3] = (__bf16)Rv[2][3];                       \
    _o[4] = (__bf16)Rv[3][0]; _o[5] = (__bf16)Rv[3][1];                       \
    _o[6] = (__bf16)Rv[3][2]; _o[7] = (__bf16)Rv[3][3];                       \
    *(bf16x8*)(_d + (size_t)(512 + t) * 8) = _o;                              \
} while (0)

#define LOAD_A(base) do {                                                     \
    _Pragma("unroll")                                                         \
    for (int _qm = 0; _qm < 4; ++_qm) {                                       \
        areg[_qm][0] = *(const bf16x8*)((base) + aoff[_qm][0]);               \
        areg[_qm][1] = *(const bf16x8*)((base) + aoff[_qm][1]);               \
    }                                                                         \
} while (0)

#define LOAD_B(base) do {                                                     \
    _Pragma("unroll")                                                         \
    for (int _qn = 0; _qn < 2; ++_qn) {                                       \
        breg[_qn][0] = *(const bf16x8*)((base) + boff[_qn][0]);               \
        breg[_qn][1] = *(const bf16x8*)((base) + boff[_qn][1]);               \
    }                                                                         \
} while (0)

// 16 MFMAs filling one C-quadrant slice (no setprio, no asm fences:
// compiler inserts exact counted lgkm waits for areg/breg uses)
#define MFMA16(MO, NO) do {                                                   \
    _Pragma("unroll")                                                         \
    for (int _qm = 0; _qm < 4; ++_qm)                                         \
        _Pragma("unroll")                                                     \
        for (int _qn = 0; _qn < 2; ++_qn) {                                   \
            acc[(MO) + _qm][(NO) + _qn] =                                     \
                __builtin_amdgcn_mfma_f32_16x16x32_bf16(                      \
                    areg[_qm][0], breg[_qn][0], acc[(MO) + _qm][(NO) + _qn],  \
                    0, 0, 0);                                                 \
            acc[(MO) + _qm][(NO) + _qn] =                                     \
                __builtin_amdgcn_mfma_f32_16x16x32_bf16(                      \
                    areg[_qm][1], breg[_qn][1], acc[(MO) + _qm][(NO) + _qn],  \
                    0, 0, 0);                                                 \
        }                                                                     \
} while (0)

#define BARR()    do { __builtin_amdgcn_s_barrier();                          \
                       asm volatile("" ::: "memory"); } while (0)
#define LGKM0()   asm volatile("s_waitcnt lgkmcnt(0)" ::: "memory")
#define VMCNT0()  asm volatile("s_waitcnt vmcnt(0)" ::: "memory")

    // ---- prologue: stage tile 0 fully ----
    B_LOAD(0, 0, Br0);
    B_LOAD(0, 1, Br1);
    STAGE_A(0, 0, 0);
    STAGE_A(0, 1, 0);
    VMCNT0();
    B_WRITE(0, 0, Br0);
    B_WRITE(1, 0, Br1);
    LGKM0();             // own ds_writes visible before barrier
    BARR();

    // ONE barrier per tile. Invariant entering tile kt: buffer P=kt&1
    // holds tile kt; no vmem outstanding. Body: issue tile kt+1 staging
    // first (B->regs, A->DMA into buffer QI=1-P), then straight-line
    // reads+MFMAs (compiler-scheduled), then vmcnt(0) + B_WRITE + lgkm0
    // + barrier. WAR: stage into QI only touches the buffer whose reads
    // all completed before the previous barrier (pre-barrier lgkm0).
#define TILE_BODY(kt, P, QI) do {                                             \
    const char* _a0 = (const char*)&As[(P)][0][0];                            \
    const char* _a1 = (const char*)&As[(P)][1][0];                            \
    const char* _b0 = (const char*)&Bs[(P)][0][0];                            \
    const char* _b1 = (const char*)&Bs[(P)][1][0];                            \
    if ((kt) + 1 < KT8) {                                                     \
        B_LOAD((kt) + 1, 0, Br0);                                             \
        B_LOAD((kt) + 1, 1, Br1);                                             \
        STAGE_A((kt) + 1, 0, QI);                                             \
        STAGE_A((kt) + 1, 1, QI);                                             \
    }                                                                         \
    LOAD_A(_a0);                                                              \
    LOAD_B(_b0);                                                              \
    MFMA16(0, 0);                                                             \
    LOAD_B(_b1);                                                              \
    MFMA16(0, 2);                                                             \
    LOAD_A(_a1);                                                              \
    MFMA16(4, 2);                                                             \
    LOAD_B(_b0);                                                              \
    MFMA16(4, 0);                                                             \
    VMCNT0();   /* Br + A-DMAs issued a full tile ago -> latency covered */   \
    if ((kt) + 1 < KT8) {                                                     \
        B_WRITE(0, QI, Br0);                                                  \
        B_WRITE(1, QI, Br1);                                                  \
    }                                                                         \
    LGKM0();    /* own reads done (WAR) + own writes visible */               \
    BARR();                                                                   \
} while (0)

    for (int it = 0; it < KT8 / 2; ++it) {
        const int kte = 2 * it;
        TILE_BODY(kte,     0, 1);
        TILE_BODY(kte + 1, 1, 0);
    }

#undef TILE_BODY
#undef STAGE_A
#undef B_LOAD
#undef B_WRITE
#undef LOAD_A
#undef LOAD_B
#undef MFMA16
#undef BARR
#undef LGKM0
#undef VMCNT0

    // epilogue. C/D layout (probe-verified): n = lane&15, m = q*4 + reg.
    // acc[mf][nf]: row = m0 + (mf>>2)*128 + (mf&3)*32 + wm*16 + q*4 + r
    //              col = n0 + (nf>>1)*128 + (nf&1)*64 + wn*16 + lidx
    float bv[4];
    #pragma unroll
    for (int nf = 0; nf < 4; ++nf)
        bv[nf] = bias[n0 + (nf >> 1) * 128 + (nf & 1) * 64 + wn * 16 + lidx];

    if (f32w) {
        float* yf = (float*)yraw;
        #pragma unroll
        for (int mf = 0; mf < 8; ++mf)
            #pragma unroll
            for (int r = 0; r < 4; ++r) {
                const int m = m0 + (mf >> 2) * 128 + (mf & 3) * 32 + wm * 16 + q * 4 + r;
                float* yp = yf + (size_t)m * OUT_F + n0 + wn * 16 + lidx;
                #pragma unroll
                for (int nf = 0; nf < 4; ++nf)
                    yp[(nf >> 1) * 128 + (nf & 1) * 64] =
                        acc[mf][nf][r] * scale + bv[nf];
            }
    } else {
        __bf16* yh = (__bf16*)yraw;
        #pragma unroll
        for (int mf = 0; mf < 8; ++mf)
            #pragma unroll
            for (int r = 0; r < 4; ++r) {
                const int m = m0 + (mf >> 2) * 128 + (mf & 3) * 32 + wm * 16 + q * 4 + r;
                __bf16* yp = yh + (size_t)m * OUT_F + n0 + wn * 16 + lidx;
                #pragma unroll
                for (int nf = 0; nf < 4; ++nf)
                    yp[(nf >> 1) * 128 + (nf & 1) * 64] =
                        (__bf16)(acc[mf][nf][r] * scale + bv[nf]);
            }
    }
}

// ---- fallback (R6 kernel): only if ws_size can't hold cvt_x buffer ----
__global__ __launch_bounds__(256) void f8linear_fallback(
    const void*  __restrict__ xraw,
    const float* __restrict__ wq,
    const float* __restrict__ w_scale,
    const float* __restrict__ bias,
    void*        __restrict__ yraw,
    const int*   __restrict__ flag_p)
{
    __shared__ __align__(16) __bf16 As[BM * 40];
    __shared__ __align__(16) __bf16 Bs[BN * 40];

    const int f32w = (*flag_p != 0);
    const int t    = threadIdx.x;
    const int lane = t & 63;
    const int wv   = t >> 6;
    const int wm   = wv >> 1;
    const int wn   = wv & 1;
    const int lidx = lane & 15;
    const int q    = lane >> 4;

    const int flat = blockIdx.x;
    const int xcd  = flat & 7;
    const int slot = flat >> 3;
    const int ni   = xcd * 14 + (slot >> 3);
    const int mi   = slot & 7;
    const int m0   = mi * BM;
    const int n0   = ni * BN;

    const float scale = w_scale[0];
    const float*  xf = (const float*)xraw;
    const __bf16* xh = (const __bf16*)xraw;

    const int af_row = t >> 3;
    const int af_col = (t & 7) * 4;
    int ah_row[2], ah_cg[2];
    #pragma unroll
    for (int i = 0; i < 2; ++i) {
        const int s = i * 256 + t;
        ah_row[i] = s >> 2;
        ah_cg[i]  = s & 3;
    }
    const int b_row = t >> 3;
    const int b_col = (t & 7) * 4;

    const f32x4 zero4 = {0.f, 0.f, 0.f, 0.f};
    f32x4 acc[4][4];
    #pragma unroll
    for (int i = 0; i < 4; ++i)
        #pragma unroll
        for (int j = 0; j < 4; ++j)
            acc[i][j] = zero4;

    f32x4  aregf[4];
    bf16x8 aregh[2];
    f32x4  breg[4];
    if (f32w) {
        #pragma unroll
        for (int i = 0; i < 4; ++i)
            aregf[i] = *reinterpret_cast<const f32x4*>(
                xf + (size_t)(m0 + af_row + i * 32) * IN_F + af_col);
    } else {
        #pragma unroll
        for (int i = 0; i < 2; ++i)
            aregh[i] = *reinterpret_cast<const bf16x8*>(
                xh + (size_t)(m0 + ah_row[i]) * IN_F + ah_cg[i] * 8);
    }
    #pragma unroll
    for (int i = 0; i < 4; ++i)
        breg[i] = *reinterpret_cast<const f32x4*>(
            wq + (size_t)(n0 + i * 32 + b_row) * IN_F + b_col);

    for (int kt = 0; kt < 128; ++kt) {
        const int k0 = kt * 32;
        if (f32w) {
            #pragma unroll
            for (int i = 0; i < 4; ++i) {
                bf16x4 pk;
                pk[0] = (__bf16)aregf[i][0];
                pk[1] = (__bf16)aregf[i][1];
                pk[2] = (__bf16)aregf[i][2];
                pk[3] = (__bf16)aregf[i][3];
                *reinterpret_cast<bf16x4*>(As + (af_row + i * 32) * 40 + af_col) = pk;
            }
        } else {
            #pragma unroll
            for (int i = 0; i < 2; ++i)
                *reinterpret_cast<bf16x8*>(As + ah_row[i] * 40 + ah_cg[i] * 8) = aregh[i];
        }
        #pragma unroll
        for (int i = 0; i < 4; ++i) {
            bf16x4 pk;
            pk[0] = (__bf16)breg[i][0];
            pk[1] = (__bf16)breg[i][1];
            pk[2] = (__bf16)breg[i][2];
            pk[3] = (__bf16)breg[i][3];
            *reinterpret_cast<bf16x4*>(Bs + (i * 32 + b_row) * 40 + b_col) = pk;
        }
        __syncthreads();
        if (kt + 1 < 128) {
            const int k1 = k0 + 32;
            if (f32w) {
                #pragma unroll
                for (int i = 0; i < 4; ++i)
                    aregf[i] = *reinterpret_cast<const f32x4*>(
                        xf + (size_t)(m0 + af_row + i * 32) * IN_F + k1 + af_col);
            } else {
                #pragma unroll
                for (int i = 0; i < 2; ++i)
                    aregh[i] = *reinterpret_cast<const bf16x8*>(
                        xh + (size_t)(m0 + ah_row[i]) * IN_F + k1 + ah_cg[i] * 8);
            }
            #pragma unroll
            for (int i = 0; i < 4; ++i)
                breg[i] = *reinterpret_cast<const f32x4*>(
                    wq + (size_t)(n0 + i * 32 + b_row) * IN_F + k1 + b_col);
        }
        bf16x8 afr[4], bfr[4];
        #pragma unroll
        for (int mt = 0; mt < 4; ++mt) {
            const int row = wm * 64 + mt * 16 + lidx;
            afr[mt] = *reinterpret_cast<const bf16x8*>(As + row * 40 + q * 8);
        }
        #pragma unroll
        for (int nt = 0; nt < 4; ++nt) {
            const int row = wn * 64 + nt * 16 + lidx;
            bfr[nt] = *reinterpret_cast<const bf16x8*>(Bs + row * 40 + q * 8);
        }
        #pragma unroll
        for (int mt = 0; mt < 4; ++mt)
            #pragma unroll
            for (int nt = 0; nt < 4; ++nt)
                acc[mt][nt] = __builtin_amdgcn_mfma_f32_16x16x32_bf16(
                    afr[mt], bfr[nt], acc[mt][nt], 0, 0, 0);
        __syncthreads();
    }

    float bv[4];
    #pragma unroll
    for (int nt = 0; nt < 4; ++nt)
        bv[nt] = bias[n0 + wn * 64 + nt * 16 + lidx];

    if (f32w) {
        float* yf = (float*)yraw;
        #pragma unroll
        for (int mt = 0; mt < 4; ++mt)
            #pragma unroll
            for (int r = 0; r < 4; ++r) {
                const int m = m0 + wm * 64 + mt * 16 + q * 4 + r;
                float* yp = yf + (size_t)m * OUT_F + n0 + wn * 64 + lidx;
                #pragma unroll
                for (int nt = 0; nt < 4; ++nt)
                    yp[nt * 16] = acc[mt][nt][r] * scale + bv[nt];
            }
    } else {
        __bf16* yh = (__bf16*)yraw;
        #pragma unroll
        for (int mt = 0; mt < 4; ++mt)
            #pragma unroll
            for (int r = 0; r < 4; ++r) {
                const int m = m0 + wm * 64 + mt * 16 + q * 4 + r;
                __bf16* yp = yh + (size_t)m * OUT_F + n0 + wn * 64 + lidx;
                #pragma unroll
                for (int nt = 0; nt < 4; ++nt)
                    yp[nt * 16] = (__bf16)(acc[mt][nt][r] * scale + bv[nt]);
            }
    }
}

extern "C" void kernel_launch(void* const* d_in, const int* in_sizes, int n_in,
                              void* d_out, int out_size, void* d_ws, size_t ws_size,
                              hipStream_t stream) {
    const void* px = nullptr; const void* pw = nullptr;
    const void* ps = nullptr; const void* pb = nullptr;
    for (int i = 0; i < n_in; ++i) {
        const long sz = in_sizes[i];
        if      (sz == (long)M_TOT * IN_F) px = d_in[i];
        else if (sz == (long)OUT_F * IN_F) pw = d_in[i];
        else if (sz == 1)                  ps = d_in[i];
        else if (sz == OUT_F)              pb = d_in[i];
    }
    if (!px) px = d_in[0];
    if (!pw) pw = d_in[1];
    if (!ps) ps = d_in[2];
    if (!pb) pb = d_in[3];

    const size_t X_BYTES  = (size_t)M_TOT * IN_F * 2;   // 8,388,608
    const size_t FLAG_OFF = X_BYTES;

    if (ws_size >= FLAG_OFF + 16) {
        __bf16* xbf  = (__bf16*)d_ws;
        int*    flag = (int*)((char*)d_ws + FLAG_OFF);

        const int grid8 = (M_TOT / TM) * (OUT_F / TN);  // 224

        detect_x_dtype<<<1, 256, 0, stream>>>((const uint32_t*)px, flag);
        cvt_x_kernel<<<2048, 256, 0, stream>>>(px, (bf16x8*)xbf, flag);
        gemm_fused_1b<<<grid8, 512, 0, stream>>>(
            xbf, (const float*)pw, (const float*)ps, (const float*)pb,
            d_out, flag);
    } else {
        int* flag = (int*)d_ws;
        const int grid = (M_TOT / BM) * (OUT_F / BN);   // 896
        detect_x_dtype<<<1, 256, 0, stream>>>((const uint32_t*)px, flag);
        f8linear_fallback<<<grid, 256, 0, stream>>>(
            px, (const float*)pw, (const float*)ps, (const float*)pb, d_out, flag);
    }
}

// Round 7
// 456.454 us; speedup vs baseline: 1.2668x; 1.0187x over previous
//
#include <hip/hip_runtime.h>
#include <hip/hip_bf16.h>
#include <stdint.h>

// F8Linear: y[m,n] = sum_k x[m,k] * (w_f8[n,k] * s) + bias[n]
// M=1024, N=14336, K=4096.
// R15: 32x32x16 MFMA core. R8/R9/R13/R14 falsified occupancy, barrier
//   count, vmcnt discipline, prefetch depth (all land 184-217 us). The
//   wall is per-tile instruction/dependency cost: 64 MFMA + 28 ds_read
//   chains per wave. 32x32x16 = 2x FLOP/instr at same operand bytes:
//   32 MFMA + 24 ds_read per tile per wave, MFMA-pipe floor -17%.
//   Fragment mapping per guide (m74/m101): A/B row|col=lane&31,
//   k=(lane>>5)*8+e; C/D col=lane&31, row=(reg&3)+8*(reg>>2)+4*(lane>>5).
//   Shell (1-barrier/tile, fused f32->bf16 B staging, swizzle) = R14.

#define IN_F   4096
#define OUT_F  14336
#define M_TOT  1024

// legacy fallback tile params
#define BM 128
#define BN 128

// main kernel params
#define TM 256
#define TN 256
#define TK 64
#define KT8 (IN_F / TK)   // 64

typedef __bf16  bf16x8 __attribute__((ext_vector_type(8)));
typedef __bf16  bf16x4 __attribute__((ext_vector_type(4)));
typedef float   f32x4  __attribute__((ext_vector_type(4)));
typedef float   f32x16 __attribute__((ext_vector_type(16)));

__device__ __forceinline__ void async_copy16(const void* g, void* l) {
    __builtin_amdgcn_global_load_lds(
        (const __attribute__((address_space(1))) void*)g,
        (__attribute__((address_space(3))) void*)l,
        16, 0, 0);
}

// ---- detector: bf16-valued f32 words have low16 == 0 over 1024 dwords ----
__global__ void detect_x_dtype(const uint32_t* __restrict__ xb,
                               int* __restrict__ flag) {
    __shared__ int any_low;
    if (threadIdx.x == 0) any_low = 0;
    __syncthreads();
    uint32_t bad = 0;
    for (int i = threadIdx.x; i < 1024; i += 256) bad |= (xb[i] & 0xFFFFu);
    if (bad) atomicOr(&any_low, 1);
    __syncthreads();
    if (threadIdx.x == 0) *flag = (any_low == 0) ? 1 : 0;
}

// ---- cvt_x: 4,194,304 elems -> bf16 (cvt f32-world, copy bf16-world) ----
__global__ __launch_bounds__(256) void cvt_x_kernel(
    const void* __restrict__ xraw, bf16x8* __restrict__ out,
    const int* __restrict__ flag) {
    const int f32w = (*flag != 0);
    const int i = blockIdx.x * 256 + threadIdx.x;   // 0..524287
    if (f32w) {
        const f32x4* in = (const f32x4*)xraw;
        f32x4 a = in[2 * i];
        f32x4 b = in[2 * i + 1];
        bf16x8 o;
        o[0] = (__bf16)a[0]; o[1] = (__bf16)a[1];
        o[2] = (__bf16)a[2]; o[3] = (__bf16)a[3];
        o[4] = (__bf16)b[0]; o[5] = (__bf16)b[1];
        o[6] = (__bf16)b[2]; o[7] = (__bf16)b[3];
        out[i] = o;
    } else {
        out[i] = ((const bf16x8*)xraw)[i];
    }
}

// ---- main GEMM: 256x256 tile, 32x32x16 MFMA, 1 barrier/tile ----
__global__ __launch_bounds__(512, 2) void gemm_fused_32(
    const __bf16* __restrict__ xb,     // [M_TOT][IN_F] bf16 (ws)
    const float*  __restrict__ wf,     // [OUT_F][IN_F] f32 (original input)
    const float*  __restrict__ w_scale,
    const float*  __restrict__ bias,
    void*         __restrict__ yraw,   // f32 or bf16 container per flag
    const int*    __restrict__ flag_p)
{
    // [dbuf][half]: half = 128 rows x 64 cols bf16 = 16 KiB. Total 128 KiB.
    __shared__ __align__(16) __bf16 As[2][2][128 * TK];
    __shared__ __align__(16) __bf16 Bs[2][2][128 * TK];

    const int f32w = (*flag_p != 0);
    const int t    = threadIdx.x;
    const int lane = t & 63;
    const int wv   = t >> 6;     // 0..7
    const int wm   = wv >> 2;    // 0..1  (M split)
    const int wn   = wv & 3;     // 0..3  (N split)
    const int l31  = lane & 31;
    const int hi   = lane >> 5;  // 0..1 (k-subgroup / row+4 in C/D)

    // 224 blocks = 8 XCDs x 28; per XCD: 7 N-panels x 4 M-tiles (M fastest)
    const int flat = blockIdx.x;
    const int xcd  = flat & 7;
    const int slot = flat >> 3;            // 0..27
    const int ni   = xcd * 7 + (slot >> 2);
    const int mi   = slot & 3;
    const int m0   = mi * TM;
    const int n0   = ni * TN;

    const float scale = w_scale[0];

    const __bf16* gA = xb + (size_t)m0 * IN_F;

    // staging geometry: half-tile = 1024 slots of 8 bf16; 512 threads x 2.
    // slot s -> row = s>>3, phys 16B-group = s&7 holds LOGICAL group
    // (s&7)^(row&7)  (conflict-free swizzle; LDS dest stays linear).
    int srow[2], scgl[2];
    #pragma unroll
    for (int i = 0; i < 2; ++i) {
        const int s = i * 512 + t;
        srow[i] = s >> 3;
        scgl[i] = (s & 7) ^ (srow[i] & 7);
    }

    // B source (f32): per-thread bases for the two slots
    const float* gB0 = wf + (size_t)(n0 + srow[0]) * IN_F + scgl[0] * 8;
    const float* gB1 = wf + (size_t)(n0 + srow[1]) * IN_F + scgl[1] * 8;

    // 32x32x16 fragment ds_read byte offsets within one half-buffer.
    // A frag (mt,ks): row r = wm*64 + (mt&1)*32 + l31 (half = mt>>1),
    //   k-group g = ks*2 + hi; addr = r*128 + ((g)^(r&7))*16.
    // B frag (nt,ks): r = (wn&1)*64 + nt*32 + l31 (half = wn>>1).
    int aoffL[2][4], boffL[2][4];
    #pragma unroll
    for (int m01 = 0; m01 < 2; ++m01) {
        const int r = wm * 64 + m01 * 32 + l31;
        #pragma unroll
        for (int ks = 0; ks < 4; ++ks)
            aoffL[m01][ks] = r * 128 + (((ks * 2 + hi) ^ (r & 7)) * 16);
    }
    #pragma unroll
    for (int nt = 0; nt < 2; ++nt) {
        const int r = (wn & 1) * 64 + nt * 32 + l31;
        #pragma unroll
        for (int ks = 0; ks < 4; ++ks)
            boffL[nt][ks] = r * 128 + (((ks * 2 + hi) ^ (r & 7)) * 16);
    }
    const int bhalf = wn >> 1;   // which B LDS half this wave reads

    const f32x16 zero16 = {0.f,0.f,0.f,0.f, 0.f,0.f,0.f,0.f,
                           0.f,0.f,0.f,0.f, 0.f,0.f,0.f,0.f};
    f32x16 acc[4][2];            // [mt][nt] 32x32 tiles -> 128 AGPR
    #pragma unroll
    for (int i = 0; i < 4; ++i) {
        acc[i][0] = zero16;
        acc[i][1] = zero16;
    }

    // single-depth B staging regs (32 VGPR) — proven no-spill footprint
    f32x4 Br0[4], Br1[4];

#define STAGE_A(tile, half, BI) do {                                          \
    __bf16* _dst = &As[(BI)][(half)][0];                                      \
    const __bf16* _src = gA + (size_t)(half) * 128 * IN_F + (tile) * TK;      \
    async_copy16(_src + (size_t)srow[0] * IN_F + scgl[0] * 8, _dst + t * 8);  \
    async_copy16(_src + (size_t)srow[1] * IN_F + scgl[1] * 8,                 \
                 _dst + (512 + t) * 8);                                       \
} while (0)

#define B_LOAD(tile, half, Rv) do {                                           \
    const float* _p0 = gB0 + (size_t)(half) * 128 * IN_F + (tile) * TK;       \
    const float* _p1 = gB1 + (size_t)(half) * 128 * IN_F + (tile) * TK;       \
    Rv[0] = *(const f32x4*)_p0;                                               \
    Rv[1] = *(const f32x4*)(_p0 + 4);                                         \
    Rv[2] = *(const f32x4*)_p1;                                               \
    Rv[3] = *(const f32x4*)(_p1 + 4);                                         \
} while (0)

#define B_WRITE(half, BI, Rv) do {                                            \
    __bf16* _d = &Bs[(BI)][(half)][0];                                        \
    bf16x8 _o;                                                                \
    _o[0] = (__bf16)Rv[0][0]; _o[1] = (__bf16)Rv[0][1];                       \
    _o[2] = (__bf16)Rv[0][2]; _o[3] = (__bf16)Rv[0][3];                       \
    _o[4] = (__bf16)Rv[1][0]; _o[5] = (__bf16)Rv[1][1];                       \
    _o[6] = (__bf16)Rv[1][2]; _o[7] = (__bf16)Rv[1][3];                       \
    *(bf16x8*)(_d + (size_t)t * 8) = _o;                                      \
    _o[0] = (__bf16)Rv[2][0]; _o[1] = (__bf16)Rv[2][1];                       \
    _o[2] = (__bf16)Rv[2][2]; _o[3] = (__bf16)Rv[2][3];                       \
    _o[4] = (__bf16)Rv[3][0]; _o[5] = (__bf16)Rv[3][1];                       \
    _o[6] = (__bf16)Rv[3][2]; _o[7] = (__bf16)Rv[3][3];                       \
    *(bf16x8*)(_d + (size_t)(512 + t) * 8) = _o;                              \
} while (0)

// one K=16 step: 6 ds_read_b128 + 8 mfma_32x32x16
#define KSTEP(a0p, a1p, bbp, ks) do {                                         \
    bf16x8 _ar0 = *(const bf16x8*)((a0p) + aoffL[0][ks]);                     \
    bf16x8 _ar1 = *(const bf16x8*)((a0p) + aoffL[1][ks]);                     \
    bf16x8 _ar2 = *(const bf16x8*)((a1p) + aoffL[0][ks]);                     \
    bf16x8 _ar3 = *(const bf16x8*)((a1p) + aoffL[1][ks]);                     \
    bf16x8 _br0 = *(const bf16x8*)((bbp) + boffL[0][ks]);                     \
    bf16x8 _br1 = *(const bf16x8*)((bbp) + boffL[1][ks]);                     \
    acc[0][0] = __builtin_amdgcn_mfma_f32_32x32x16_bf16(_ar0, _br0, acc[0][0], 0, 0, 0); \
    acc[0][1] = __builtin_amdgcn_mfma_f32_32x32x16_bf16(_ar0, _br1, acc[0][1], 0, 0, 0); \
    acc[1][0] = __builtin_amdgcn_mfma_f32_32x32x16_bf16(_ar1, _br0, acc[1][0], 0, 0, 0); \
    acc[1][1] = __builtin_amdgcn_mfma_f32_32x32x16_bf16(_ar1, _br1, acc[1][1], 0, 0, 0); \
    acc[2][0] = __builtin_amdgcn_mfma_f32_32x32x16_bf16(_ar2, _br0, acc[2][0], 0, 0, 0); \
    acc[2][1] = __builtin_amdgcn_mfma_f32_32x32x16_bf16(_ar2, _br1, acc[2][1], 0, 0, 0); \
    acc[3][0] = __builtin_amdgcn_mfma_f32_32x32x16_bf16(_ar3, _br0, acc[3][0], 0, 0, 0); \
    acc[3][1] = __builtin_amdgcn_mfma_f32_32x32x16_bf16(_ar3, _br1, acc[3][1], 0, 0, 0); \
} while (0)

#define BARR()    do { __builtin_amdgcn_s_barrier();                          \
                       asm volatile("" ::: "memory"); } while (0)
#define LGKM0()   asm volatile("s_waitcnt lgkmcnt(0)" ::: "memory")
#define VMCNT0()  asm volatile("s_waitcnt vmcnt(0)" ::: "memory")

    // ---- prologue: stage tile 0 fully ----
    B_LOAD(0, 0, Br0);
    B_LOAD(0, 1, Br1);
    STAGE_A(0, 0, 0);
    STAGE_A(0, 1, 0);
    VMCNT0();
    B_WRITE(0, 0, Br0);
    B_WRITE(1, 0, Br1);
    LGKM0();             // own ds_writes visible before barrier
    BARR();

    // ONE barrier per tile (R14 shell). Invariant entering tile kt:
    // buffer P=kt&1 holds tile kt; no vmem outstanding for this wave's
    // consumption. Issue kt+1 staging first, then 4 KSTEPs (compiler-
    // scheduled counted lgkm waits), then vmcnt(0)+B_WRITE+lgkm0+barrier.
#define TILE_BODY(kt, P, QI) do {                                             \
    const char* _a0 = (const char*)&As[(P)][0][0];                            \
    const char* _a1 = (const char*)&As[(P)][1][0];                            \
    const char* _bb = (const char*)&Bs[(P)][bhalf][0];                        \
    if ((kt) + 1 < KT8) {                                                     \
        B_LOAD((kt) + 1, 0, Br0);                                             \
        B_LOAD((kt) + 1, 1, Br1);                                             \
        STAGE_A((kt) + 1, 0, QI);                                             \
        STAGE_A((kt) + 1, 1, QI);                                             \
    }                                                                         \
    KSTEP(_a0, _a1, _bb, 0);                                                  \
    KSTEP(_a0, _a1, _bb, 1);                                                  \
    KSTEP(_a0, _a1, _bb, 2);                                                  \
    KSTEP(_a0, _a1, _bb, 3);                                                  \
    VMCNT0();   /* Br + A-DMAs issued a full tile ago -> latency covered */   \
    if ((kt) + 1 < KT8) {                                                     \
        B_WRITE(0, QI, Br0);                                                  \
        B_WRITE(1, QI, Br1);                                                  \
    }                                                                         \
    LGKM0();    /* own reads done (WAR) + own writes visible */               \
    BARR();                                                                   \
} while (0)

    for (int it = 0; it < KT8 / 2; ++it) {
        const int kte = 2 * it;
        TILE_BODY(kte,     0, 1);
        TILE_BODY(kte + 1, 1, 0);
    }

#undef TILE_BODY
#undef STAGE_A
#undef B_LOAD
#undef B_WRITE
#undef KSTEP
#undef BARR
#undef LGKM0
#undef VMCNT0

    // epilogue. 32x32 C/D layout (guide m74/m101): col = lane&31,
    // row = (reg&3) + 8*(reg>>2) + 4*hi.
    // acc[mt][nt]: grow = m0 + (mt>>1)*128 + wm*64 + (mt&1)*32 + row
    //              gcol = n0 + (wn>>1)*128 + (wn&1)*64 + nt*32 + l31
    const int colbase = n0 + (wn >> 1) * 128 + (wn & 1) * 64 + l31;
    float bv[2];
    bv[0] = bias[colbase];
    bv[1] = bias[colbase + 32];

    if (f32w) {
        float* yf = (float*)yraw;
        #pragma unroll
        for (int mt = 0; mt < 4; ++mt) {
            const int rowbase = m0 + (mt >> 1) * 128 + wm * 64 + (mt & 1) * 32 + 4 * hi;
            #pragma unroll
            for (int r = 0; r < 16; ++r) {
                const int grow = rowbase + (r & 3) + 8 * (r >> 2);
                float* yp = yf + (size_t)grow * OUT_F + colbase;
                yp[0]  = acc[mt][0][r] * scale + bv[0];
                yp[32] = acc[mt][1][r] * scale + bv[1];
            }
        }
    } else {
        __bf16* yh = (__bf16*)yraw;
        #pragma unroll
        for (int mt = 0; mt < 4; ++mt) {
            const int rowbase = m0 + (mt >> 1) * 128 + wm * 64 + (mt & 1) * 32 + 4 * hi;
            #pragma unroll
            for (int r = 0; r < 16; ++r) {
                const int grow = rowbase + (r & 3) + 8 * (r >> 2);
                __bf16* yp = yh + (size_t)grow * OUT_F + colbase;
                yp[0]  = (__bf16)(acc[mt][0][r] * scale + bv[0]);
                yp[32] = (__bf16)(acc[mt][1][r] * scale + bv[1]);
            }
        }
    }
}

// ---- fallback (R6 kernel): only if ws_size can't hold cvt_x buffer ----
__global__ __launch_bounds__(256) void f8linear_fallback(
    const void*  __restrict__ xraw,
    const float* __restrict__ wq,
    const float* __restrict__ w_scale,
    const float* __restrict__ bias,
    void*        __restrict__ yraw,
    const int*   __restrict__ flag_p)
{
    __shared__ __align__(16) __bf16 As[BM * 40];
    __shared__ __align__(16) __bf16 Bs[BN * 40];

    const int f32w = (*flag_p != 0);
    const int t    = threadIdx.x;
    const int lane = t & 63;
    const int wv   = t >> 6;
    const int wm   = wv >> 1;
    const int wn   = wv & 1;
    const int lidx = lane & 15;
    const int q    = lane >> 4;

    const int flat = blockIdx.x;
    const int xcd  = flat & 7;
    const int slot = flat >> 3;
    const int ni   = xcd * 14 + (slot >> 3);
    const int mi   = slot & 7;
    const int m0   = mi * BM;
    const int n0   = ni * BN;

    const float scale = w_scale[0];
    const float*  xf = (const float*)xraw;
    const __bf16* xh = (const __bf16*)xraw;

    const int af_row = t >> 3;
    const int af_col = (t & 7) * 4;
    int ah_row[2], ah_cg[2];
    #pragma unroll
    for (int i = 0; i < 2; ++i) {
        const int s = i * 256 + t;
        ah_row[i] = s >> 2;
        ah_cg[i]  = s & 3;
    }
    const int b_row = t >> 3;
    const int b_col = (t & 7) * 4;

    const f32x4 zero4 = {0.f, 0.f, 0.f, 0.f};
    f32x4 acc[4][4];
    #pragma unroll
    for (int i = 0; i < 4; ++i)
        #pragma unroll
        for (int j = 0; j < 4; ++j)
            acc[i][j] = zero4;

    f32x4  aregf[4];
    bf16x8 aregh[2];
    f32x4  breg[4];
    if (f32w) {
        #pragma unroll
        for (int i = 0; i < 4; ++i)
            aregf[i] = *reinterpret_cast<const f32x4*>(
                xf + (size_t)(m0 + af_row + i * 32) * IN_F + af_col);
    } else {
        #pragma unroll
        for (int i = 0; i < 2; ++i)
            aregh[i] = *reinterpret_cast<const bf16x8*>(
                xh + (size_t)(m0 + ah_row[i]) * IN_F + ah_cg[i] * 8);
    }
    #pragma unroll
    for (int i = 0; i < 4; ++i)
        breg[i] = *reinterpret_cast<const f32x4*>(
            wq + (size_t)(n0 + i * 32 + b_row) * IN_F + b_col);

    for (int kt = 0; kt < 128; ++kt) {
        const int k0 = kt * 32;
        if (f32w) {
            #pragma unroll
            for (int i = 0; i < 4; ++i) {
                bf16x4 pk;
                pk[0] = (__bf16)aregf[i][0];
                pk[1] = (__bf16)aregf[i][1];
                pk[2] = (__bf16)aregf[i][2];
                pk[3] = (__bf16)aregf[i][3];
                *reinterpret_cast<bf16x4*>(As + (af_row + i * 32) * 40 + af_col) = pk;
            }
        } else {
            #pragma unroll
            for (int i = 0; i < 2; ++i)
                *reinterpret_cast<bf16x8*>(As + ah_row[i] * 40 + ah_cg[i] * 8) = aregh[i];
        }
        #pragma unroll
        for (int i = 0; i < 4; ++i) {
            bf16x4 pk;
            pk[0] = (__bf16)breg[i][0];
            pk[1] = (__bf16)breg[i][1];
            pk[2] = (__bf16)breg[i][2];
            pk[3] = (__bf16)breg[i][3];
            *reinterpret_cast<bf16x4*>(Bs + (i * 32 + b_row) * 40 + b_col) = pk;
        }
        __syncthreads();
        if (kt + 1 < 128) {
            const int k1 = k0 + 32;
            if (f32w) {
                #pragma unroll
                for (int i = 0; i < 4; ++i)
                    aregf[i] = *reinterpret_cast<const f32x4*>(
                        xf + (size_t)(m0 + af_row + i * 32) * IN_F + k1 + af_col);
            } else {
                #pragma unroll
                for (int i = 0; i < 2; ++i)
                    aregh[i] = *reinterpret_cast<const bf16x8*>(
                        xh + (size_t)(m0 + ah_row[i]) * IN_F + k1 + ah_cg[i] * 8);
            }
            #pragma unroll
            for (int i = 0; i < 4; ++i)
                breg[i] = *reinterpret_cast<const f32x4*>(
                    wq + (size_t)(n0 + i * 32 + b_row) * IN_F + k1 + b_col);
        }
        bf16x8 afr[4], bfr[4];
        #pragma unroll
        for (int mt = 0; mt < 4; ++mt) {
            const int row = wm * 64 + mt * 16 + lidx;
            afr[mt] = *reinterpret_cast<const bf16x8*>(As + row * 40 + q * 8);
        }
        #pragma unroll
        for (int nt = 0; nt < 4; ++nt) {
            const int row = wn * 64 + nt * 16 + lidx;
            bfr[nt] = *reinterpret_cast<const bf16x8*>(Bs + row * 40 + q * 8);
        }
        #pragma unroll
        for (int mt = 0; mt < 4; ++mt)
            #pragma unroll
            for (int nt = 0; nt < 4; ++nt)
                acc[mt][nt] = __builtin_amdgcn_mfma_f32_16x16x32_bf16(
                    afr[mt], bfr[nt], acc[mt][nt], 0, 0, 0);
        __syncthreads();
    }

    float bv[4];
    #pragma unroll
    for (int nt = 0; nt < 4; ++nt)
        bv[nt] = bias[n0 + wn * 64 + nt * 16 + lidx];

    if (f32w) {
        float* yf = (float*)yraw;
        #pragma unroll
        for (int mt = 0; mt < 4; ++mt)
            #pragma unroll
            for (int r = 0; r < 4; ++r) {
                const int m = m0 + wm * 64 + mt * 16 + q * 4 + r;
                float* yp = yf + (size_t)m * OUT_F + n0 + wn * 64 + lidx;
                #pragma unroll
                for (int nt = 0; nt < 4; ++nt)
                    yp[nt * 16] = acc[mt][nt][r] * scale + bv[nt];
            }
    } else {
        __bf16* yh = (__bf16*)yraw;
        #pragma unroll
        for (int mt = 0; mt < 4; ++mt)
            #pragma unroll
            for (int r = 0; r < 4; ++r) {
                const int m = m0 + wm * 64 + mt * 16 + q * 4 + r;
                __bf16* yp = yh + (size_t)m * OUT_F + n0 + wn * 64 + lidx;
                #pragma unroll
                for (int nt = 0; nt < 4; ++nt)
                    yp[nt * 16] = (__bf16)(acc[mt][nt][r] * scale + bv[nt]);
            }
    }
}

extern "C" void kernel_launch(void* const* d_in, const int* in_sizes, int n_in,
                              void* d_out, int out_size, void* d_ws, size_t ws_size,
                              hipStream_t stream) {
    const void* px = nullptr; const void* pw = nullptr;
    const void* ps = nullptr; const void* pb = nullptr;
    for (int i = 0; i < n_in; ++i) {
        const long sz = in_sizes[i];
        if      (sz == (long)M_TOT * IN_F) px = d_in[i];
        else if (sz == (long)OUT_F * IN_F) pw = d_in[i];
        else if (sz == 1)                  ps = d_in[i];
        else if (sz == OUT_F)              pb = d_in[i];
    }
    if (!px) px = d_in[0];
    if (!pw) pw = d_in[1];
    if (!ps) ps = d_in[2];
    if (!pb) pb = d_in[3];

    const size_t X_BYTES  = (size_t)M_TOT * IN_F * 2;   // 8,388,608
    const size_t FLAG_OFF = X_BYTES;

    if (ws_size >= FLAG_OFF + 16) {
        __bf16* xbf  = (__bf16*)d_ws;
        int*    flag = (int*)((char*)d_ws + FLAG_OFF);

        const int grid8 = (M_TOT / TM) * (OUT_F / TN);  // 224

        detect_x_dtype<<<1, 256, 0, stream>>>((const uint32_t*)px, flag);
        cvt_x_kernel<<<2048, 256, 0, stream>>>(px, (bf16x8*)xbf, flag);
        gemm_fused_32<<<grid8, 512, 0, stream>>>(
            xbf, (const float*)pw, (const float*)ps, (const float*)pb,
            d_out, flag);
    } else {
        int* flag = (int*)d_ws;
        const int grid = (M_TOT / BM) * (OUT_F / BN);   // 896
        detect_x_dtype<<<1, 256, 0, stream>>>((const uint32_t*)px, flag);
        f8linear_fallback<<<grid, 256, 0, stream>>>(
            px, (const float*)pw, (const float*)ps, (const float*)pb, d_out, flag);
    }
}